// Round 5
// baseline (1412.286 us; speedup 1.0000x reference)
//
#include <hip/hip_runtime.h>
#include <hip/hip_fp16.h>
#include <math.h>

#define THREADS 256
#define KC 32
#define BSHIFT 9          // 512 nodes per bucket
#define BNODES (1 << BSHIFT)

__device__ __forceinline__ float clipf(float v){ return fminf(fmaxf(v, -10.f), 10.f); }

typedef __attribute__((ext_vector_type(8))) short bf16x8;
typedef __attribute__((ext_vector_type(4))) float f32x4;

// split fp32 into bf16 hi + bf16 lo (3-term split-GEMM decomposition)
__device__ __forceinline__ void split_bf16(float f, short& hi, short& lo){
    union { float f; unsigned u; } a; a.f = f;
    unsigned r = (a.u + 0x7FFFu + ((a.u >> 16) & 1u)) & 0xFFFF0000u;
    hi = (short)(r >> 16);
    union { unsigned u; float f; } b; b.u = r;
    float rem = f - b.f;
    union { float f; unsigned u; } c; c.f = rem;
    unsigned r2 = c.u + 0x7FFFu + ((c.u >> 16) & 1u);
    lo = (short)(r2 >> 16);
}

// ---------------------------------------------------------------- CSR build
__global__ __launch_bounds__(256) void count_deg(const int* __restrict__ dstv, int E, int* __restrict__ deg){
    int i = blockIdx.x*256 + threadIdx.x;
    if (i < E) atomicAdd(&deg[dstv[i]], 1);
}

#define SCAN_CHUNK 1024
__global__ __launch_bounds__(256) void scan1(const int* __restrict__ deg, int N, int* __restrict__ row_start, int* __restrict__ chunksum){
    __shared__ int sh[256];
    int b = blockIdx.x, t = threadIdx.x;
    int base = b*SCAN_CHUNK + t*4;
    int d0 = (base+0 < N) ? deg[base+0] : 0;
    int d1 = (base+1 < N) ? deg[base+1] : 0;
    int d2 = (base+2 < N) ? deg[base+2] : 0;
    int d3 = (base+3 < N) ? deg[base+3] : 0;
    int ts = d0+d1+d2+d3;
    sh[t] = ts; __syncthreads();
    for (int off = 1; off < 256; off <<= 1){
        int v = (t >= off) ? sh[t-off] : 0;
        __syncthreads();
        sh[t] += v;
        __syncthreads();
    }
    int ex = sh[t] - ts;
    if (base+0 < N) row_start[base+0] = ex;
    if (base+1 < N) row_start[base+1] = ex + d0;
    if (base+2 < N) row_start[base+2] = ex + d0 + d1;
    if (base+3 < N) row_start[base+3] = ex + d0 + d1 + d2;
    if (t == 255) chunksum[b] = sh[255];
}

// valid for nb <= 256 (N=100000 -> nb=98)
__global__ __launch_bounds__(256) void scan2(int* __restrict__ chunksum, int nb){
    __shared__ int sh[256];
    int t = threadIdx.x;
    int v = (t < nb) ? chunksum[t] : 0;
    sh[t] = v; __syncthreads();
    for (int off = 1; off < 256; off <<= 1){
        int u = (t >= off) ? sh[t-off] : 0;
        __syncthreads();
        sh[t] += u;
        __syncthreads();
    }
    if (t < nb) chunksum[t] = sh[t] - v;   // exclusive
}

__global__ __launch_bounds__(256) void scan3(int* __restrict__ row_start, const int* __restrict__ chunksum, int N, int E){
    int i = blockIdx.x*256 + threadIdx.x;
    if (i < N) row_start[i] += chunksum[i >> 10];
    if (i == 0) row_start[N] = E;
}

__global__ __launch_bounds__(256) void init_bcur(const int* __restrict__ row_start, int* __restrict__ bcur, int nbuckets, int N){
    int b = blockIdx.x*256 + threadIdx.x;
    if (b < nbuckets) bcur[b] = row_start[min(b << BSHIFT, N)];
}

// pass B: bin (dst,src) pairs by dst>>BSHIFT; monotone per-bucket cursors => sequential writes per bucket
__global__ __launch_bounds__(256) void bin_edges(const int* __restrict__ srcv, const int* __restrict__ dstv, int E,
                                                 int* __restrict__ bcur, int2* __restrict__ pairs){
    int i = blockIdx.x*256 + threadIdx.x;
    if (i < E){
        int d = dstv[i];
        int pos = atomicAdd(&bcur[d >> BSHIFT], 1);
        pairs[pos] = make_int2(d, srcv[i]);
    }
}

// pass C: one wg per bucket; LDS cursors; col_idx writes confined to an L2-hot window
__global__ __launch_bounds__(256) void fill_bucket(const int2* __restrict__ pairs, const int* __restrict__ row_start,
                                                   int* __restrict__ col_idx, int N){
    __shared__ int cur[BNODES];
    int n0 = blockIdx.x << BSHIFT;
    int n1 = min(n0 + BNODES, N);
    for (int i = threadIdx.x; i < BNODES; i += 256) cur[i] = 0;
    __syncthreads();
    int s = row_start[n0], e = row_start[n1];
    for (int i = s + threadIdx.x; i < e; i += 256){
        int2 p = pairs[i];
        int loc = atomicAdd(&cur[p.x - n0], 1);
        col_idx[row_start[p.x] + loc] = p.y;
    }
}

__global__ __launch_bounds__(256) void flag_users(const int* __restrict__ uid, int B, int* __restrict__ flag){
    int i = blockIdx.x*256 + threadIdx.x;
    if (i < B) flag[uid[i]] = 1;
}

__global__ __launch_bounds__(256) void compact_flags(const int* __restrict__ flag, int N, int* __restrict__ list, int* __restrict__ cnt){
    int i = blockIdx.x*256 + threadIdx.x;
    if (i < N && flag[i]){ int p = atomicAdd(cnt, 1); list[p] = i; }
}

// ---------------------------------------------------------------- x -> fp16 copy (for layer-0 gather)
__global__ __launch_bounds__(256) void convert_fp16(const float* __restrict__ in, __half* __restrict__ out, long n8){
    long t = (long)blockIdx.x*256 + threadIdx.x;
    if (t >= n8) return;
    long i = t*8;
    float4 a = *(const float4*)(in + i);
    float4 b = *(const float4*)(in + i + 4);
    union { __half2 h[4]; float4 f; } u;
    u.h[0] = __floats2half2_rn(a.x, a.y);
    u.h[1] = __floats2half2_rn(a.z, a.w);
    u.h[2] = __floats2half2_rn(b.x, b.y);
    u.h[3] = __floats2half2_rn(b.z, b.w);
    *(float4*)(out + i) = u.f;
}

// ---------------------------------------------------------------- fused weight prep (one launch)
// [0,32768)        prep_wt0 split-bf16:  wt0h/wt0l [n][k] k<128->w_l0, else w_r0
// [32768,65536)    wt1  : w_l1 / w_r1 transposed to [256][128]
// [65536,98304)    wtc0 : wc0 [128][256] -> [256][128]
// [98304,106496)   wtc1 : wc1 [64][128]  -> [128][64]
// [106496,204800)  wtg  : w_ih gather-transpose to [256][384] (i,g,o rows only)
// [204800,205184)  bias : bsum + ohtab
__global__ __launch_bounds__(256) void prep_all(const float* __restrict__ w_l0, const float* __restrict__ w_r0,
                                                const float* __restrict__ w_l1, const float* __restrict__ w_r1,
                                                const float* __restrict__ wc0,  const float* __restrict__ wc1,
                                                const float* __restrict__ w_ih, const float* __restrict__ b_ih,
                                                const float* __restrict__ b_hh,
                                                short* __restrict__ wt0h, short* __restrict__ wt0l,
                                                float* __restrict__ wt1, float* __restrict__ wtc0,
                                                float* __restrict__ wtc1, float* __restrict__ wtg,
                                                float* __restrict__ bsum, float* __restrict__ ohtab){
    int idx = blockIdx.x*256 + threadIdx.x;
    if (idx < 32768){
        int n = idx >> 8, k = idx & 255;
        float f = (k < 128) ? w_l0[n*128 + k] : w_r0[n*128 + (k - 128)];
        short h, l; split_bf16(f, h, l);
        wt0h[idx] = h; wt0l[idx] = l;
    } else if (idx < 65536){
        int i = idx - 32768;
        int which = i >> 14, e = i & 16383;
        int j = e >> 7, k = e & 127;
        const float* w = which ? w_r1 : w_l1;
        wt1[(which*128 + k)*128 + j] = w[j*128 + k];
    } else if (idx < 98304){
        int i = idx - 65536;
        int j = i >> 8, k = i & 255;
        wtc0[k*128 + j] = wc0[j*256 + k];
    } else if (idx < 106496){
        int i = idx - 98304;
        int j = i >> 7, k = i & 127;
        wtc1[k*64 + j] = wc1[j*128 + k];
    } else if (idx < 204800){
        int i = idx - 106496;
        int jj = i % 384, k = i / 384;
        int j = jj + ((jj >= 128) ? 128 : 0);
        wtg[k*384 + jj] = w_ih[j*261 + k];
    } else if (idx < 205184){
        int jj = idx - 204800;
        int j = jj + ((jj >= 128) ? 128 : 0);
        bsum[jj] = b_ih[j] + b_hh[j];
        for (int r = 0; r < 5; ++r) ohtab[r*384 + jj] = w_ih[j*261 + 256 + r];
    }
}

// ---------------------------------------------------------------- layer-0 mean aggregation (fp16 gather, fp32 accum)
__device__ __forceinline__ void accumh(float4& a0, float4& a1, float4 v){
    const __half2* h = (const __half2*)&v;
    float2 f0 = __half22float2(h[0]);
    float2 f1 = __half22float2(h[1]);
    float2 f2 = __half22float2(h[2]);
    float2 f3 = __half22float2(h[3]);
    a0.x += f0.x; a0.y += f0.y; a0.z += f1.x; a0.w += f1.y;
    a1.x += f2.x; a1.y += f2.y; a1.z += f3.x; a1.w += f3.y;
}

__global__ __launch_bounds__(256) void aggregate_h16(const __half* __restrict__ feat, const int* __restrict__ row_start,
                                                     const int* __restrict__ col_idx,
                                                     float* __restrict__ outmean, int N){
    int wave = (blockIdx.x*256 + threadIdx.x) >> 6;
    if (wave >= N) return;
    int lane = threadIdx.x & 63;
    int g  = lane >> 4;
    int sl = lane & 15;
    int s = row_start[wave], e = row_start[wave+1];
    const float4* f16 = (const float4*)feat;
    float4 a0 = make_float4(0.f,0.f,0.f,0.f);
    float4 a1 = make_float4(0.f,0.f,0.f,0.f);
    int i = s + g;
    for (; i + 12 < e; i += 16){
        int s0 = col_idx[i];
        int s1 = col_idx[i+4];
        int s2 = col_idx[i+8];
        int s3 = col_idx[i+12];
        float4 v0 = f16[(long)s0*16 + sl];
        float4 v1 = f16[(long)s1*16 + sl];
        float4 v2 = f16[(long)s2*16 + sl];
        float4 v3 = f16[(long)s3*16 + sl];
        accumh(a0, a1, v0);
        accumh(a0, a1, v1);
        accumh(a0, a1, v2);
        accumh(a0, a1, v3);
    }
    for (; i < e; i += 4){
        float4 v0 = f16[(long)col_idx[i]*16 + sl];
        accumh(a0, a1, v0);
    }
    a0.x += __shfl_xor(a0.x, 16, 64); a0.x += __shfl_xor(a0.x, 32, 64);
    a0.y += __shfl_xor(a0.y, 16, 64); a0.y += __shfl_xor(a0.y, 32, 64);
    a0.z += __shfl_xor(a0.z, 16, 64); a0.z += __shfl_xor(a0.z, 32, 64);
    a0.w += __shfl_xor(a0.w, 16, 64); a0.w += __shfl_xor(a0.w, 32, 64);
    a1.x += __shfl_xor(a1.x, 16, 64); a1.x += __shfl_xor(a1.x, 32, 64);
    a1.y += __shfl_xor(a1.y, 16, 64); a1.y += __shfl_xor(a1.y, 32, 64);
    a1.z += __shfl_xor(a1.z, 16, 64); a1.z += __shfl_xor(a1.z, 32, 64);
    a1.w += __shfl_xor(a1.w, 16, 64); a1.w += __shfl_xor(a1.w, 32, 64);
    if (g == 0){
        float inv = 1.f / fmaxf((float)(e - s), 1.f);
        a0.x *= inv; a0.y *= inv; a0.z *= inv; a0.w *= inv;
        a1.x *= inv; a1.y *= inv; a1.z *= inv; a1.w *= inv;
        float4* om = (float4*)(outmean + (long)wave*128 + sl*8);
        om[0] = a0;
        om[1] = a1;
    }
}

// ---------------------------------------------------------------- layer-1 mean aggregation (fp32 gather, compacted list)
__global__ __launch_bounds__(256) void aggregate_k(const float* __restrict__ feat, const int* __restrict__ row_start,
                                                   const int* __restrict__ col_idx,
                                                   const int* __restrict__ list, const int* __restrict__ cnt,
                                                   float* __restrict__ outmean, int N){
    int wave = (blockIdx.x*256 + threadIdx.x) >> 6;
    int lane = threadIdx.x & 63;
    if (wave >= *cnt) return;
    int node = list[wave];
    int s = row_start[node], e = row_start[node+1];
    int half = lane >> 5;
    int sl   = lane & 31;
    const float4* feat4 = (const float4*)feat;
    float4 a0 = make_float4(0.f,0.f,0.f,0.f);
    float4 a1 = make_float4(0.f,0.f,0.f,0.f);
    int i = s + half;
    for (; i + 6 < e; i += 8){
        int s0 = col_idx[i];
        int s1 = col_idx[i+2];
        int s2 = col_idx[i+4];
        int s3 = col_idx[i+6];
        float4 v0 = feat4[(long)s0*32 + sl];
        float4 v1 = feat4[(long)s1*32 + sl];
        float4 v2 = feat4[(long)s2*32 + sl];
        float4 v3 = feat4[(long)s3*32 + sl];
        a0.x += v0.x + v1.x; a0.y += v0.y + v1.y; a0.z += v0.z + v1.z; a0.w += v0.w + v1.w;
        a1.x += v2.x + v3.x; a1.y += v2.y + v3.y; a1.z += v2.z + v3.z; a1.w += v2.w + v3.w;
    }
    for (; i < e; i += 2){
        int s0 = col_idx[i];
        float4 v0 = feat4[(long)s0*32 + sl];
        a0.x += v0.x; a0.y += v0.y; a0.z += v0.z; a0.w += v0.w;
    }
    a0.x += a1.x; a0.y += a1.y; a0.z += a1.z; a0.w += a1.w;
    a0.x += __shfl_xor(a0.x, 32, 64);
    a0.y += __shfl_xor(a0.y, 32, 64);
    a0.z += __shfl_xor(a0.z, 32, 64);
    a0.w += __shfl_xor(a0.w, 32, 64);
    if (half == 0){
        float inv = 1.f / fmaxf((float)(e - s), 1.f);
        a0.x *= inv; a0.y *= inv; a0.z *= inv; a0.w *= inv;
        ((float4*)outmean)[(long)node*32 + sl] = a0;
    }
}

// ---------------------------------------------------------------- MODE-0 GEMM via split-bf16 MFMA
#define AROW 40
__global__ __launch_bounds__(256) void gemm0_mfma(const float* __restrict__ mean0, const float* __restrict__ x,
                                                  const short* __restrict__ wh, const short* __restrict__ wl,
                                                  const float* __restrict__ bias, float* __restrict__ out, int M){
    __shared__ __align__(16) short Ah[64*AROW];
    __shared__ __align__(16) short Al[64*AROW];
    __shared__ __align__(16) short Wh[128*AROW];
    __shared__ __align__(16) short Wl[128*AROW];

    const int tid  = threadIdx.x;
    const int row0 = blockIdx.x * 64;
    const int wave = tid >> 6, lane = tid & 63;
    const int lm = lane & 15, quad = lane >> 4;

    f32x4 acc[8];
    #pragma unroll
    for (int t = 0; t < 8; ++t) acc[t] = (f32x4){0.f, 0.f, 0.f, 0.f};

    for (int ko = 0; ko < 256; ko += KC){
        const float* Asrc = (ko < 128) ? (mean0 + ko) : (x + (ko - 128));
        #pragma unroll
        for (int it = 0; it < 2; ++it){
            int idx = it*256 + tid;
            int r = idx >> 3, k4 = idx & 7;
            int grow = row0 + r; if (grow >= M) grow = M - 1;
            float4 v = *(const float4*)(Asrc + (long)grow*128 + k4*4);
            union { short s[4]; int2 p; } ph, pl;
            split_bf16(v.x, ph.s[0], pl.s[0]);
            split_bf16(v.y, ph.s[1], pl.s[1]);
            split_bf16(v.z, ph.s[2], pl.s[2]);
            split_bf16(v.w, ph.s[3], pl.s[3]);
            *(int2*)&Ah[r*AROW + k4*4] = ph.p;
            *(int2*)&Al[r*AROW + k4*4] = pl.p;
        }
        #pragma unroll
        for (int it = 0; it < 2; ++it){
            int idx = it*256 + tid;
            int n = idx >> 2, q = idx & 3;
            int4 vh = *(const int4*)(wh + (long)n*256 + ko + q*8);
            *(int4*)&Wh[n*AROW + q*8] = vh;
            int4 vlo = *(const int4*)(wl + (long)n*256 + ko + q*8);
            *(int4*)&Wl[n*AROW + q*8] = vlo;
        }
        __syncthreads();

        bf16x8 ah = *(const bf16x8*)&Ah[(wave*16 + lm)*AROW + quad*8];
        bf16x8 al = *(const bf16x8*)&Al[(wave*16 + lm)*AROW + quad*8];
        #pragma unroll
        for (int t = 0; t < 8; ++t){
            bf16x8 bh = *(const bf16x8*)&Wh[(t*16 + lm)*AROW + quad*8];
            bf16x8 bl = *(const bf16x8*)&Wl[(t*16 + lm)*AROW + quad*8];
            acc[t] = __builtin_amdgcn_mfma_f32_16x16x32_bf16(ah, bh, acc[t], 0, 0, 0);
            acc[t] = __builtin_amdgcn_mfma_f32_16x16x32_bf16(ah, bl, acc[t], 0, 0, 0);
            acc[t] = __builtin_amdgcn_mfma_f32_16x16x32_bf16(al, bh, acc[t], 0, 0, 0);
        }
        __syncthreads();
    }

    #pragma unroll
    for (int t = 0; t < 8; ++t){
        int col = t*16 + lm;
        float b = bias[col];
        #pragma unroll
        for (int r = 0; r < 4; ++r){
            int row = row0 + wave*16 + quad*4 + r;
            if (row < M) out[(long)row*128 + col] = fmaxf(acc[t][r] + b, 0.f);
        }
    }
}

// ---------------------------------------------------------------- generic fp32 GEMM (modes 1-4)
struct GemmArgs {
    const float* a0; const float* a1; const int* g;
    const float* wt; int ncolsW;
    const float* bias; const float* ohtab; const int* roles;
    float* out; int ncolsOut; int M;
};

template<int MODE>
__device__ __forceinline__ float4 load_a(const GemmArgs& A, int row, int k){
    if constexpr (MODE == 1){
        int node = A.g[row];
        const float* p = (k < 128) ? A.a0 + (long)node*128 + k : A.a1 + (long)node*128 + (k-128);
        return *(const float4*)p;
    } else if constexpr (MODE == 2){
        if (k < 128) return *(const float4*)(A.a0 + (long)row*128 + k);
        int node = A.g[row];
        float4 v = *(const float4*)(A.a1 + (long)node*128 + (k-128));
        v.x = clipf(v.x); v.y = clipf(v.y); v.z = clipf(v.z); v.w = clipf(v.w);
        return v;
    } else if constexpr (MODE == 4){
        return *(const float4*)(A.a0 + (long)row*128 + k);
    } else {
        const float* p = (k < 128) ? A.a0 + (long)row*128 + k : A.a1 + (long)row*128 + (k-128);
        return *(const float4*)p;
    }
}

template<int MODE>
__global__ __launch_bounds__(THREADS) void gemm_k(GemmArgs A){
    constexpr int BM = 64;
    constexpr int BN = (MODE == 4) ? 64 : 128;
    constexpr int TN = 4;
    constexpr int CT = BN / TN;
    constexpr int RT = THREADS / CT;
    constexpr int TM = BM / RT;
    constexpr int KTOT = (MODE == 4) ? 128 : 256;
    constexpr int AST = BM + 4;

    __shared__ __align__(16) float As[KC][AST];
    __shared__ __align__(16) float Ws[KC][BN];

    const int tid  = threadIdx.x;
    const int row0 = blockIdx.x * BM;
    const int col0 = blockIdx.y * BN;
    const int c  = tid % CT;
    const int rt = tid / CT;

    float acc[TM][TN];
    #pragma unroll
    for (int i = 0; i < TM; ++i)
        #pragma unroll
        for (int j = 0; j < TN; ++j) acc[i][j] = 0.f;

    for (int ko = 0; ko < KTOT; ko += KC){
        #pragma unroll
        for (int it = 0; it < (BM*KC/4)/THREADS; ++it){
            int idx = it*THREADS + tid;
            int r  = idx >> 3;
            int k4 = idx & 7;
            int grow = row0 + r; if (grow >= A.M) grow = A.M - 1;
            float4 v = load_a<MODE>(A, grow, ko + k4*4);
            As[k4*4+0][r] = v.x;
            As[k4*4+1][r] = v.y;
            As[k4*4+2][r] = v.z;
            As[k4*4+3][r] = v.w;
        }
        #pragma unroll
        for (int it = 0; it < (KC*BN/4)/THREADS; ++it){
            int idx = it*THREADS + tid;
            int kk = idx / (BN/4);
            int c4 = idx % (BN/4);
            float4 v = *(const float4*)&A.wt[(long)(ko+kk)*A.ncolsW + col0 + c4*4];
            *(float4*)&Ws[kk][c4*4] = v;
        }
        __syncthreads();
        #pragma unroll
        for (int kk = 0; kk < KC; ++kk){
            float4 wv = *(const float4*)&Ws[kk][c*4];
            float w[TN] = {wv.x, wv.y, wv.z, wv.w};
            float a[TM];
            #pragma unroll
            for (int q = 0; q < TM/4; ++q){
                float4 av = *(const float4*)&As[kk][rt*TM + q*4];
                a[q*4+0] = av.x; a[q*4+1] = av.y; a[q*4+2] = av.z; a[q*4+3] = av.w;
            }
            #pragma unroll
            for (int i = 0; i < TM; ++i)
                #pragma unroll
                for (int j = 0; j < TN; ++j) acc[i][j] = fmaf(a[i], w[j], acc[i][j]);
        }
        __syncthreads();
    }

    #pragma unroll
    for (int i = 0; i < TM; ++i){
        int grow = row0 + rt*TM + i;
        if (grow >= A.M) continue;
        #pragma unroll
        for (int j = 0; j < TN; ++j){
            int gcol = col0 + c*4 + j;
            float v = acc[i][j];
            if constexpr (MODE == 0)      v = fmaxf(v + A.bias[gcol], 0.f);
            else if constexpr (MODE == 1) v = clipf(v + A.bias[gcol]);
            else if constexpr (MODE == 2) v = v + A.bias[gcol] + A.ohtab[A.roles[grow]*384 + gcol];
            else                          v = fmaxf(v + A.bias[gcol], 0.f);
            A.out[(long)grow*A.ncolsOut + gcol] = v;
        }
    }
}

// ---------------------------------------------------------------- LSTM activation (f-gate dead, c0=0)
__global__ __launch_bounds__(256) void lstm_act(const float* __restrict__ gates, float* __restrict__ lstm, int B){
    int idx = blockIdx.x*256 + threadIdx.x;
    if (idx >= B*128) return;
    int b = idx >> 7, j = idx & 127;
    const float* gr = gates + (long)b*384;
    float i_ = gr[j], g_ = gr[128 + j], o_ = gr[256 + j];
    float si = 1.f/(1.f + expf(-i_));
    float c  = si * tanhf(g_);
    float so = 1.f/(1.f + expf(-o_));
    lstm[idx] = clipf(so * tanhf(c));
}

// ---------------------------------------------------------------- final tiny GEMM [B,64]@[64,5]
__global__ __launch_bounds__(256) void out_k(const float* __restrict__ z1, const float* __restrict__ wc2, const float* __restrict__ bc2,
                                             float* __restrict__ out, int B){
    int idx = blockIdx.x*256 + threadIdx.x;
    int b = idx >> 3, r = idx & 7;
    if (b >= B || r >= 5) return;
    const float* zr = z1 + (long)b*64;
    const float* wr = wc2 + r*64;
    float acc = bc2[r];
    #pragma unroll 16
    for (int k = 0; k < 64; ++k) acc = fmaf(zr[k], wr[k], acc);
    out[b*5 + r] = acc;
}

// ----------------------------------------------------------------
extern "C" void kernel_launch(void* const* d_in, const int* in_sizes, int n_in,
                              void* d_out, int out_size, void* d_ws, size_t ws_size,
                              hipStream_t stream){
    const float* x     = (const float*)d_in[0];
    const int*   edge  = (const int*)  d_in[1];
    const int*   uid   = (const int*)  d_in[2];
    const int*   roles = (const int*)  d_in[3];
    const float* w_l0  = (const float*)d_in[4];
    const float* b_l0  = (const float*)d_in[5];
    const float* w_r0  = (const float*)d_in[6];
    const float* w_l1  = (const float*)d_in[7];
    const float* b_l1  = (const float*)d_in[8];
    const float* w_r1  = (const float*)d_in[9];
    const float* w_ih  = (const float*)d_in[10];
    // d_in[11] = w_hh: dead (h0 = 0)
    const float* b_ih  = (const float*)d_in[12];
    const float* b_hh  = (const float*)d_in[13];
    const float* wc0   = (const float*)d_in[14];
    const float* bc0   = (const float*)d_in[15];
    const float* wc1   = (const float*)d_in[16];
    const float* bc1   = (const float*)d_in[17];
    const float* wc2   = (const float*)d_in[18];
    const float* bc2   = (const float*)d_in[19];

    const int N = in_sizes[0] / 128;
    const int E = in_sizes[1] / 2;
    const int B = in_sizes[2];
    const int nbuckets = (N + BNODES - 1) >> BSHIFT;

    char* ws = (char*)d_ws;
    size_t off = 0;
    auto alloc = [&](size_t bytes) -> void* {
        void* p = ws + off; off += (bytes + 255) & ~(size_t)255; return p;
    };
    float* arenaA   = (float*)alloc((size_t)N*128*4);   // mean0 -> mean1 -> gates
    float* arenaB   = (float*)alloc((size_t)N*128*4);   // pairs -> h -> lstm/z0/z1
    float* ue       = (float*)alloc((size_t)B*128*4);
    __half* xh      = (__half*)alloc((size_t)N*128*2);
    // zero-init region (one memset): degi, flag, ucnt
    int*   degi     = (int*)  alloc((size_t)N*4);
    int*   flag     = (int*)  alloc((size_t)N*4);
    int*   ucnt     = (int*)  alloc(256);
    char*  zero_end = ws + off;
    int*   row_start= (int*)  alloc((size_t)(N+1)*4);
    int*   chunksum = (int*)  alloc(1024*4);
    int*   bcur     = (int*)  alloc((size_t)nbuckets*4);
    int*   col_idx  = (int*)  alloc((size_t)E*4);
    int*   ulist    = (int*)  alloc((size_t)B*4);
    short* wt0h     = (short*)alloc(128*256*2);
    short* wt0l     = (short*)alloc(128*256*2);
    float* wt1      = (float*)alloc(256*128*4);
    float* wtg      = (float*)alloc(256*384*4);
    float* bsum     = (float*)alloc(384*4);
    float* ohtab    = (float*)alloc(5*384*4);
    float* wtc0     = (float*)alloc(256*128*4);
    float* wtc1     = (float*)alloc(128*64*4);

    int2*  pairs = (int2*)arenaB;                // consumed by fill_bucket before h is written
    float* mean0 = arenaA;
    float* h     = arenaB;
    float* mean1 = arenaA;
    float* gates = arenaA;
    float* lstm  = arenaB;
    float* z0    = arenaB + (size_t)B*128;
    float* z1    = arenaB + (size_t)B*128*2;

    hipMemsetAsync(degi, 0, (size_t)(zero_end - (char*)degi), stream);

    const int gE = (E + 255)/256;
    const int nchunk = (N + SCAN_CHUNK - 1)/SCAN_CHUNK;

    count_deg<<<gE, 256, 0, stream>>>(edge + E, E, degi);
    scan1<<<nchunk, 256, 0, stream>>>(degi, N, row_start, chunksum);
    scan2<<<1, 256, 0, stream>>>(chunksum, nchunk);
    scan3<<<(N + 255)/256, 256, 0, stream>>>(row_start, chunksum, N, E);
    init_bcur<<<(nbuckets + 255)/256, 256, 0, stream>>>(row_start, bcur, nbuckets, N);
    bin_edges<<<gE, 256, 0, stream>>>(edge, edge + E, E, bcur, pairs);
    fill_bucket<<<nbuckets, 256, 0, stream>>>(pairs, row_start, col_idx, N);
    flag_users<<<(B + 255)/256, 256, 0, stream>>>(uid, B, flag);
    compact_flags<<<(N + 255)/256, 256, 0, stream>>>(flag, N, ulist, ucnt);

    convert_fp16<<<(N*128/8 + 255)/256, 256, 0, stream>>>(x, xh, (long)N*128/8);
    prep_all<<<802, 256, 0, stream>>>(w_l0, w_r0, w_l1, w_r1, wc0, wc1, w_ih, b_ih, b_hh,
                                      wt0h, wt0l, wt1, wtc0, wtc1, wtg, bsum, ohtab);

    // layer 0: mean over all nodes (fp16 gather), then h = relu([mean0|x] @ wt0^T + b_l0) via MFMA
    aggregate_h16<<<(N + 3)/4, 256, 0, stream>>>(xh, row_start, col_idx, mean0, N);
    gemm0_mfma<<<(N + 63)/64, 256, 0, stream>>>(mean0, x, wt0h, wt0l, b_l0, h, N);

    // layer 1: aggregation + dense only for user nodes (compacted list, fp32 gather)
    aggregate_k<<<(B + 3)/4, 256, 0, stream>>>(h, row_start, col_idx, ulist, ucnt, mean1, N);
    GemmArgs gu { mean1, h, uid, wt1, 128, b_l1, nullptr, nullptr, ue, 128, B };
    gemm_k<1><<<dim3(B/64, 1), THREADS, 0, stream>>>(gu);

    // LSTM gates (i,g,o only) + activation
    GemmArgs gg { ue, x, uid, wtg, 384, bsum, ohtab, roles, gates, 384, B };
    gemm_k<2><<<dim3(B/64, 3), THREADS, 0, stream>>>(gg);
    lstm_act<<<(B*128 + 255)/256, 256, 0, stream>>>(gates, lstm, B);

    // classifier MLP
    GemmArgs gz0 { ue, lstm, nullptr, wtc0, 128, bc0, nullptr, nullptr, z0, 128, B };
    gemm_k<3><<<dim3(B/64, 1), THREADS, 0, stream>>>(gz0);
    GemmArgs gz1 { z0, nullptr, nullptr, wtc1, 64, bc1, nullptr, nullptr, z1, 64, B };
    gemm_k<4><<<dim3(B/64, 1), THREADS, 0, stream>>>(gz1);
    out_k<<<(B*8 + 255)/256, 256, 0, stream>>>(z1, wc2, bc2, (float*)d_out, B);

    (void)n_in; (void)out_size; (void)ws_size;
}

// Round 6
// 543.261 us; speedup vs baseline: 2.5996x; 2.5996x over previous
//
#include <hip/hip_runtime.h>
#include <hip/hip_fp16.h>
#include <math.h>

#define THREADS 256
#define KC 32
#define BSHIFT 9          // 512 nodes per bucket
#define BNODES (1 << BSHIFT)
#define NB_MAX 256        // max buckets (N<=131072)
#define ECHUNK 4096       // edges per block in bin_edges_priv

__device__ __forceinline__ float clipf(float v){ return fminf(fmaxf(v, -10.f), 10.f); }

typedef __attribute__((ext_vector_type(8))) short bf16x8;
typedef __attribute__((ext_vector_type(4))) float f32x4;

// split fp32 into bf16 hi + bf16 lo (3-term split-GEMM decomposition)
__device__ __forceinline__ void split_bf16(float f, short& hi, short& lo){
    union { float f; unsigned u; } a; a.f = f;
    unsigned r = (a.u + 0x7FFFu + ((a.u >> 16) & 1u)) & 0xFFFF0000u;
    hi = (short)(r >> 16);
    union { unsigned u; float f; } b; b.u = r;
    float rem = f - b.f;
    union { float f; unsigned u; } c; c.f = rem;
    unsigned r2 = c.u + 0x7FFFu + ((c.u >> 16) & 1u);
    lo = (short)(r2 >> 16);
}

// ---------------------------------------------------------------- CSR build
__global__ __launch_bounds__(256) void count_deg(const int* __restrict__ dstv, int E, int* __restrict__ deg){
    int i = blockIdx.x*256 + threadIdx.x;
    if (i < E) atomicAdd(&deg[dstv[i]], 1);
}

#define SCAN_CHUNK 1024
__global__ __launch_bounds__(256) void scan1(const int* __restrict__ deg, int N, int* __restrict__ row_start, int* __restrict__ chunksum){
    __shared__ int sh[256];
    int b = blockIdx.x, t = threadIdx.x;
    int base = b*SCAN_CHUNK + t*4;
    int d0 = (base+0 < N) ? deg[base+0] : 0;
    int d1 = (base+1 < N) ? deg[base+1] : 0;
    int d2 = (base+2 < N) ? deg[base+2] : 0;
    int d3 = (base+3 < N) ? deg[base+3] : 0;
    int ts = d0+d1+d2+d3;
    sh[t] = ts; __syncthreads();
    for (int off = 1; off < 256; off <<= 1){
        int v = (t >= off) ? sh[t-off] : 0;
        __syncthreads();
        sh[t] += v;
        __syncthreads();
    }
    int ex = sh[t] - ts;
    if (base+0 < N) row_start[base+0] = ex;
    if (base+1 < N) row_start[base+1] = ex + d0;
    if (base+2 < N) row_start[base+2] = ex + d0 + d1;
    if (base+3 < N) row_start[base+3] = ex + d0 + d1 + d2;
    if (t == 255) chunksum[b] = sh[255];
}

// valid for nb <= 256 (N=100000 -> nb=98)
__global__ __launch_bounds__(256) void scan2(int* __restrict__ chunksum, int nb){
    __shared__ int sh[256];
    int t = threadIdx.x;
    int v = (t < nb) ? chunksum[t] : 0;
    sh[t] = v; __syncthreads();
    for (int off = 1; off < 256; off <<= 1){
        int u = (t >= off) ? sh[t-off] : 0;
        __syncthreads();
        sh[t] += u;
        __syncthreads();
    }
    if (t < nb) chunksum[t] = sh[t] - v;   // exclusive
}

__global__ __launch_bounds__(256) void scan3(int* __restrict__ row_start, const int* __restrict__ chunksum, int N, int E){
    int i = blockIdx.x*256 + threadIdx.x;
    if (i < N) row_start[i] += chunksum[i >> 10];
    if (i == 0) row_start[N] = E;
}

__global__ __launch_bounds__(256) void init_bcur(const int* __restrict__ row_start, int* __restrict__ bcur, int nbuckets, int N){
    int b = blockIdx.x*256 + threadIdx.x;
    if (b < nbuckets) bcur[b] = row_start[min(b << BSHIFT, N)];
}

// pass B (privatized): each block bins an ECHUNK-edge slice.
// LDS histogram -> one global atomicAdd per (block,bucket) -> LDS-cursor scatter
// into block-private contiguous ranges (single writer per front => no line thrash).
__global__ __launch_bounds__(256) void bin_edges_priv(const int* __restrict__ srcv, const int* __restrict__ dstv, int E,
                                                      int nbuckets, int* __restrict__ bcur, int2* __restrict__ pairs){
    __shared__ int cnt[NB_MAX];
    __shared__ int base[NB_MAX];
    int b0 = blockIdx.x * ECHUNK;
    int b1 = min(b0 + ECHUNK, E);
    for (int i = threadIdx.x; i < nbuckets; i += 256) cnt[i] = 0;
    __syncthreads();
    for (int i = b0 + threadIdx.x; i < b1; i += 256)
        atomicAdd(&cnt[dstv[i] >> BSHIFT], 1);
    __syncthreads();
    for (int i = threadIdx.x; i < nbuckets; i += 256){
        int c = cnt[i];
        base[i] = c ? atomicAdd(&bcur[i], c) : 0;
    }
    __syncthreads();
    for (int i = threadIdx.x; i < nbuckets; i += 256) cnt[i] = 0;
    __syncthreads();
    for (int i = b0 + threadIdx.x; i < b1; i += 256){
        int d = dstv[i];
        int bk = d >> BSHIFT;
        int loc = atomicAdd(&cnt[bk], 1);
        pairs[base[bk] + loc] = make_int2(d, srcv[i]);
    }
}

// pass C: one wg per bucket; LDS cursors; col_idx writes confined to an L2-hot window
__global__ __launch_bounds__(256) void fill_bucket(const int2* __restrict__ pairs, const int* __restrict__ row_start,
                                                   int* __restrict__ col_idx, int N){
    __shared__ int cur[BNODES];
    int n0 = blockIdx.x << BSHIFT;
    int n1 = min(n0 + BNODES, N);
    for (int i = threadIdx.x; i < BNODES; i += 256) cur[i] = 0;
    __syncthreads();
    int s = row_start[n0], e = row_start[n1];
    for (int i = s + threadIdx.x; i < e; i += 256){
        int2 p = pairs[i];
        int loc = atomicAdd(&cur[p.x - n0], 1);
        col_idx[row_start[p.x] + loc] = p.y;
    }
}

__global__ __launch_bounds__(256) void flag_users(const int* __restrict__ uid, int B, int* __restrict__ flag){
    int i = blockIdx.x*256 + threadIdx.x;
    if (i < B) flag[uid[i]] = 1;
}

__global__ __launch_bounds__(256) void compact_flags(const int* __restrict__ flag, int N, int* __restrict__ list, int* __restrict__ cnt){
    int i = blockIdx.x*256 + threadIdx.x;
    if (i < N && flag[i]){ int p = atomicAdd(cnt, 1); list[p] = i; }
}

// ---------------------------------------------------------------- x -> fp16 copy (for layer-0 gather)
__global__ __launch_bounds__(256) void convert_fp16(const float* __restrict__ in, __half* __restrict__ out, long n8){
    long t = (long)blockIdx.x*256 + threadIdx.x;
    if (t >= n8) return;
    long i = t*8;
    float4 a = *(const float4*)(in + i);
    float4 b = *(const float4*)(in + i + 4);
    union { __half2 h[4]; float4 f; } u;
    u.h[0] = __floats2half2_rn(a.x, a.y);
    u.h[1] = __floats2half2_rn(a.z, a.w);
    u.h[2] = __floats2half2_rn(b.x, b.y);
    u.h[3] = __floats2half2_rn(b.z, b.w);
    *(float4*)(out + i) = u.f;
}

// ---------------------------------------------------------------- fused weight prep (one launch)
__global__ __launch_bounds__(256) void prep_all(const float* __restrict__ w_l0, const float* __restrict__ w_r0,
                                                const float* __restrict__ w_l1, const float* __restrict__ w_r1,
                                                const float* __restrict__ wc0,  const float* __restrict__ wc1,
                                                const float* __restrict__ w_ih, const float* __restrict__ b_ih,
                                                const float* __restrict__ b_hh,
                                                short* __restrict__ wt0h, short* __restrict__ wt0l,
                                                float* __restrict__ wt1, float* __restrict__ wtc0,
                                                float* __restrict__ wtc1, float* __restrict__ wtg,
                                                float* __restrict__ bsum, float* __restrict__ ohtab){
    int idx = blockIdx.x*256 + threadIdx.x;
    if (idx < 32768){
        int n = idx >> 8, k = idx & 255;
        float f = (k < 128) ? w_l0[n*128 + k] : w_r0[n*128 + (k - 128)];
        short h, l; split_bf16(f, h, l);
        wt0h[idx] = h; wt0l[idx] = l;
    } else if (idx < 65536){
        int i = idx - 32768;
        int which = i >> 14, e = i & 16383;
        int j = e >> 7, k = e & 127;
        const float* w = which ? w_r1 : w_l1;
        wt1[(which*128 + k)*128 + j] = w[j*128 + k];
    } else if (idx < 98304){
        int i = idx - 65536;
        int j = i >> 8, k = i & 255;
        wtc0[k*128 + j] = wc0[j*256 + k];
    } else if (idx < 106496){
        int i = idx - 98304;
        int j = i >> 7, k = i & 127;
        wtc1[k*64 + j] = wc1[j*128 + k];
    } else if (idx < 204800){
        int i = idx - 106496;
        int jj = i % 384, k = i / 384;
        int j = jj + ((jj >= 128) ? 128 : 0);
        wtg[k*384 + jj] = w_ih[j*261 + k];
    } else if (idx < 205184){
        int jj = idx - 204800;
        int j = jj + ((jj >= 128) ? 128 : 0);
        bsum[jj] = b_ih[j] + b_hh[j];
        for (int r = 0; r < 5; ++r) ohtab[r*384 + jj] = w_ih[j*261 + 256 + r];
    }
}

// ---------------------------------------------------------------- layer-0 mean aggregation (fp16 gather, fp32 accum)
__device__ __forceinline__ void accumh(float4& a0, float4& a1, float4 v){
    const __half2* h = (const __half2*)&v;
    float2 f0 = __half22float2(h[0]);
    float2 f1 = __half22float2(h[1]);
    float2 f2 = __half22float2(h[2]);
    float2 f3 = __half22float2(h[3]);
    a0.x += f0.x; a0.y += f0.y; a0.z += f1.x; a0.w += f1.y;
    a1.x += f2.x; a1.y += f2.y; a1.z += f3.x; a1.w += f3.y;
}

__global__ __launch_bounds__(256) void aggregate_h16(const __half* __restrict__ feat, const int* __restrict__ row_start,
                                                     const int* __restrict__ col_idx,
                                                     float* __restrict__ outmean, int N){
    int wave = (blockIdx.x*256 + threadIdx.x) >> 6;
    if (wave >= N) return;
    int lane = threadIdx.x & 63;
    int g  = lane >> 4;
    int sl = lane & 15;
    int s = row_start[wave], e = row_start[wave+1];
    const float4* f16 = (const float4*)feat;
    float4 a0 = make_float4(0.f,0.f,0.f,0.f);
    float4 a1 = make_float4(0.f,0.f,0.f,0.f);
    int i = s + g;
    for (; i + 12 < e; i += 16){
        int s0 = col_idx[i];
        int s1 = col_idx[i+4];
        int s2 = col_idx[i+8];
        int s3 = col_idx[i+12];
        float4 v0 = f16[(long)s0*16 + sl];
        float4 v1 = f16[(long)s1*16 + sl];
        float4 v2 = f16[(long)s2*16 + sl];
        float4 v3 = f16[(long)s3*16 + sl];
        accumh(a0, a1, v0);
        accumh(a0, a1, v1);
        accumh(a0, a1, v2);
        accumh(a0, a1, v3);
    }
    for (; i < e; i += 4){
        float4 v0 = f16[(long)col_idx[i]*16 + sl];
        accumh(a0, a1, v0);
    }
    a0.x += __shfl_xor(a0.x, 16, 64); a0.x += __shfl_xor(a0.x, 32, 64);
    a0.y += __shfl_xor(a0.y, 16, 64); a0.y += __shfl_xor(a0.y, 32, 64);
    a0.z += __shfl_xor(a0.z, 16, 64); a0.z += __shfl_xor(a0.z, 32, 64);
    a0.w += __shfl_xor(a0.w, 16, 64); a0.w += __shfl_xor(a0.w, 32, 64);
    a1.x += __shfl_xor(a1.x, 16, 64); a1.x += __shfl_xor(a1.x, 32, 64);
    a1.y += __shfl_xor(a1.y, 16, 64); a1.y += __shfl_xor(a1.y, 32, 64);
    a1.z += __shfl_xor(a1.z, 16, 64); a1.z += __shfl_xor(a1.z, 32, 64);
    a1.w += __shfl_xor(a1.w, 16, 64); a1.w += __shfl_xor(a1.w, 32, 64);
    if (g == 0){
        float inv = 1.f / fmaxf((float)(e - s), 1.f);
        a0.x *= inv; a0.y *= inv; a0.z *= inv; a0.w *= inv;
        a1.x *= inv; a1.y *= inv; a1.z *= inv; a1.w *= inv;
        float4* om = (float4*)(outmean + (long)wave*128 + sl*8);
        om[0] = a0;
        om[1] = a1;
    }
}

// ---------------------------------------------------------------- layer-1 mean aggregation (fp32 gather, compacted list)
__global__ __launch_bounds__(256) void aggregate_k(const float* __restrict__ feat, const int* __restrict__ row_start,
                                                   const int* __restrict__ col_idx,
                                                   const int* __restrict__ list, const int* __restrict__ cnt,
                                                   float* __restrict__ outmean, int N){
    int wave = (blockIdx.x*256 + threadIdx.x) >> 6;
    int lane = threadIdx.x & 63;
    if (wave >= *cnt) return;
    int node = list[wave];
    int s = row_start[node], e = row_start[node+1];
    int half = lane >> 5;
    int sl   = lane & 31;
    const float4* feat4 = (const float4*)feat;
    float4 a0 = make_float4(0.f,0.f,0.f,0.f);
    float4 a1 = make_float4(0.f,0.f,0.f,0.f);
    int i = s + half;
    for (; i + 6 < e; i += 8){
        int s0 = col_idx[i];
        int s1 = col_idx[i+2];
        int s2 = col_idx[i+4];
        int s3 = col_idx[i+6];
        float4 v0 = feat4[(long)s0*32 + sl];
        float4 v1 = feat4[(long)s1*32 + sl];
        float4 v2 = feat4[(long)s2*32 + sl];
        float4 v3 = feat4[(long)s3*32 + sl];
        a0.x += v0.x + v1.x; a0.y += v0.y + v1.y; a0.z += v0.z + v1.z; a0.w += v0.w + v1.w;
        a1.x += v2.x + v3.x; a1.y += v2.y + v3.y; a1.z += v2.z + v3.z; a1.w += v2.w + v3.w;
    }
    for (; i < e; i += 2){
        int s0 = col_idx[i];
        float4 v0 = feat4[(long)s0*32 + sl];
        a0.x += v0.x; a0.y += v0.y; a0.z += v0.z; a0.w += v0.w;
    }
    a0.x += a1.x; a0.y += a1.y; a0.z += a1.z; a0.w += a1.w;
    a0.x += __shfl_xor(a0.x, 32, 64);
    a0.y += __shfl_xor(a0.y, 32, 64);
    a0.z += __shfl_xor(a0.z, 32, 64);
    a0.w += __shfl_xor(a0.w, 32, 64);
    if (half == 0){
        float inv = 1.f / fmaxf((float)(e - s), 1.f);
        a0.x *= inv; a0.y *= inv; a0.z *= inv; a0.w *= inv;
        ((float4*)outmean)[(long)node*32 + sl] = a0;
    }
}

// ---------------------------------------------------------------- MODE-0 GEMM via split-bf16 MFMA
#define AROW 40
__global__ __launch_bounds__(256) void gemm0_mfma(const float* __restrict__ mean0, const float* __restrict__ x,
                                                  const short* __restrict__ wh, const short* __restrict__ wl,
                                                  const float* __restrict__ bias, float* __restrict__ out, int M){
    __shared__ __align__(16) short Ah[64*AROW];
    __shared__ __align__(16) short Al[64*AROW];
    __shared__ __align__(16) short Wh[128*AROW];
    __shared__ __align__(16) short Wl[128*AROW];

    const int tid  = threadIdx.x;
    const int row0 = blockIdx.x * 64;
    const int wave = tid >> 6, lane = tid & 63;
    const int lm = lane & 15, quad = lane >> 4;

    f32x4 acc[8];
    #pragma unroll
    for (int t = 0; t < 8; ++t) acc[t] = (f32x4){0.f, 0.f, 0.f, 0.f};

    for (int ko = 0; ko < 256; ko += KC){
        const float* Asrc = (ko < 128) ? (mean0 + ko) : (x + (ko - 128));
        #pragma unroll
        for (int it = 0; it < 2; ++it){
            int idx = it*256 + tid;
            int r = idx >> 3, k4 = idx & 7;
            int grow = row0 + r; if (grow >= M) grow = M - 1;
            float4 v = *(const float4*)(Asrc + (long)grow*128 + k4*4);
            union { short s[4]; int2 p; } ph, pl;
            split_bf16(v.x, ph.s[0], pl.s[0]);
            split_bf16(v.y, ph.s[1], pl.s[1]);
            split_bf16(v.z, ph.s[2], pl.s[2]);
            split_bf16(v.w, ph.s[3], pl.s[3]);
            *(int2*)&Ah[r*AROW + k4*4] = ph.p;
            *(int2*)&Al[r*AROW + k4*4] = pl.p;
        }
        #pragma unroll
        for (int it = 0; it < 2; ++it){
            int idx = it*256 + tid;
            int n = idx >> 2, q = idx & 3;
            int4 vh = *(const int4*)(wh + (long)n*256 + ko + q*8);
            *(int4*)&Wh[n*AROW + q*8] = vh;
            int4 vlo = *(const int4*)(wl + (long)n*256 + ko + q*8);
            *(int4*)&Wl[n*AROW + q*8] = vlo;
        }
        __syncthreads();

        bf16x8 ah = *(const bf16x8*)&Ah[(wave*16 + lm)*AROW + quad*8];
        bf16x8 al = *(const bf16x8*)&Al[(wave*16 + lm)*AROW + quad*8];
        #pragma unroll
        for (int t = 0; t < 8; ++t){
            bf16x8 bh = *(const bf16x8*)&Wh[(t*16 + lm)*AROW + quad*8];
            bf16x8 bl = *(const bf16x8*)&Wl[(t*16 + lm)*AROW + quad*8];
            acc[t] = __builtin_amdgcn_mfma_f32_16x16x32_bf16(ah, bh, acc[t], 0, 0, 0);
            acc[t] = __builtin_amdgcn_mfma_f32_16x16x32_bf16(ah, bl, acc[t], 0, 0, 0);
            acc[t] = __builtin_amdgcn_mfma_f32_16x16x32_bf16(al, bh, acc[t], 0, 0, 0);
        }
        __syncthreads();
    }

    #pragma unroll
    for (int t = 0; t < 8; ++t){
        int col = t*16 + lm;
        float b = bias[col];
        #pragma unroll
        for (int r = 0; r < 4; ++r){
            int row = row0 + wave*16 + quad*4 + r;
            if (row < M) out[(long)row*128 + col] = fmaxf(acc[t][r] + b, 0.f);
        }
    }
}

// ---------------------------------------------------------------- generic fp32 GEMM (modes 1-4)
struct GemmArgs {
    const float* a0; const float* a1; const int* g;
    const float* wt; int ncolsW;
    const float* bias; const float* ohtab; const int* roles;
    float* out; int ncolsOut; int M;
};

template<int MODE>
__device__ __forceinline__ float4 load_a(const GemmArgs& A, int row, int k){
    if constexpr (MODE == 1){
        int node = A.g[row];
        const float* p = (k < 128) ? A.a0 + (long)node*128 + k : A.a1 + (long)node*128 + (k-128);
        return *(const float4*)p;
    } else if constexpr (MODE == 2){
        if (k < 128) return *(const float4*)(A.a0 + (long)row*128 + k);
        int node = A.g[row];
        float4 v = *(const float4*)(A.a1 + (long)node*128 + (k-128));
        v.x = clipf(v.x); v.y = clipf(v.y); v.z = clipf(v.z); v.w = clipf(v.w);
        return v;
    } else if constexpr (MODE == 4){
        return *(const float4*)(A.a0 + (long)row*128 + k);
    } else {
        const float* p = (k < 128) ? A.a0 + (long)row*128 + k : A.a1 + (long)row*128 + (k-128);
        return *(const float4*)p;
    }
}

template<int MODE>
__global__ __launch_bounds__(THREADS) void gemm_k(GemmArgs A){
    constexpr int BM = 64;
    constexpr int BN = (MODE == 4) ? 64 : 128;
    constexpr int TN = 4;
    constexpr int CT = BN / TN;
    constexpr int RT = THREADS / CT;
    constexpr int TM = BM / RT;
    constexpr int KTOT = (MODE == 4) ? 128 : 256;
    constexpr int AST = BM + 4;

    __shared__ __align__(16) float As[KC][AST];
    __shared__ __align__(16) float Ws[KC][BN];

    const int tid  = threadIdx.x;
    const int row0 = blockIdx.x * BM;
    const int col0 = blockIdx.y * BN;
    const int c  = tid % CT;
    const int rt = tid / CT;

    float acc[TM][TN];
    #pragma unroll
    for (int i = 0; i < TM; ++i)
        #pragma unroll
        for (int j = 0; j < TN; ++j) acc[i][j] = 0.f;

    for (int ko = 0; ko < KTOT; ko += KC){
        #pragma unroll
        for (int it = 0; it < (BM*KC/4)/THREADS; ++it){
            int idx = it*THREADS + tid;
            int r  = idx >> 3;
            int k4 = idx & 7;
            int grow = row0 + r; if (grow >= A.M) grow = A.M - 1;
            float4 v = load_a<MODE>(A, grow, ko + k4*4);
            As[k4*4+0][r] = v.x;
            As[k4*4+1][r] = v.y;
            As[k4*4+2][r] = v.z;
            As[k4*4+3][r] = v.w;
        }
        #pragma unroll
        for (int it = 0; it < (KC*BN/4)/THREADS; ++it){
            int idx = it*THREADS + tid;
            int kk = idx / (BN/4);
            int c4 = idx % (BN/4);
            float4 v = *(const float4*)&A.wt[(long)(ko+kk)*A.ncolsW + col0 + c4*4];
            *(float4*)&Ws[kk][c4*4] = v;
        }
        __syncthreads();
        #pragma unroll
        for (int kk = 0; kk < KC; ++kk){
            float4 wv = *(const float4*)&Ws[kk][c*4];
            float w[TN] = {wv.x, wv.y, wv.z, wv.w};
            float a[TM];
            #pragma unroll
            for (int q = 0; q < TM/4; ++q){
                float4 av = *(const float4*)&As[kk][rt*TM + q*4];
                a[q*4+0] = av.x; a[q*4+1] = av.y; a[q*4+2] = av.z; a[q*4+3] = av.w;
            }
            #pragma unroll
            for (int i = 0; i < TM; ++i)
                #pragma unroll
                for (int j = 0; j < TN; ++j) acc[i][j] = fmaf(a[i], w[j], acc[i][j]);
        }
        __syncthreads();
    }

    #pragma unroll
    for (int i = 0; i < TM; ++i){
        int grow = row0 + rt*TM + i;
        if (grow >= A.M) continue;
        #pragma unroll
        for (int j = 0; j < TN; ++j){
            int gcol = col0 + c*4 + j;
            float v = acc[i][j];
            if constexpr (MODE == 0)      v = fmaxf(v + A.bias[gcol], 0.f);
            else if constexpr (MODE == 1) v = clipf(v + A.bias[gcol]);
            else if constexpr (MODE == 2) v = v + A.bias[gcol] + A.ohtab[A.roles[grow]*384 + gcol];
            else                          v = fmaxf(v + A.bias[gcol], 0.f);
            A.out[(long)grow*A.ncolsOut + gcol] = v;
        }
    }
}

// ---------------------------------------------------------------- LSTM activation (f-gate dead, c0=0)
__global__ __launch_bounds__(256) void lstm_act(const float* __restrict__ gates, float* __restrict__ lstm, int B){
    int idx = blockIdx.x*256 + threadIdx.x;
    if (idx >= B*128) return;
    int b = idx >> 7, j = idx & 127;
    const float* gr = gates + (long)b*384;
    float i_ = gr[j], g_ = gr[128 + j], o_ = gr[256 + j];
    float si = 1.f/(1.f + expf(-i_));
    float c  = si * tanhf(g_);
    float so = 1.f/(1.f + expf(-o_));
    lstm[idx] = clipf(so * tanhf(c));
}

// ---------------------------------------------------------------- final tiny GEMM [B,64]@[64,5]
__global__ __launch_bounds__(256) void out_k(const float* __restrict__ z1, const float* __restrict__ wc2, const float* __restrict__ bc2,
                                             float* __restrict__ out, int B){
    int idx = blockIdx.x*256 + threadIdx.x;
    int b = idx >> 3, r = idx & 7;
    if (b >= B || r >= 5) return;
    const float* zr = z1 + (long)b*64;
    const float* wr = wc2 + r*64;
    float acc = bc2[r];
    #pragma unroll 16
    for (int k = 0; k < 64; ++k) acc = fmaf(zr[k], wr[k], acc);
    out[b*5 + r] = acc;
}

// ----------------------------------------------------------------
extern "C" void kernel_launch(void* const* d_in, const int* in_sizes, int n_in,
                              void* d_out, int out_size, void* d_ws, size_t ws_size,
                              hipStream_t stream){
    const float* x     = (const float*)d_in[0];
    const int*   edge  = (const int*)  d_in[1];
    const int*   uid   = (const int*)  d_in[2];
    const int*   roles = (const int*)  d_in[3];
    const float* w_l0  = (const float*)d_in[4];
    const float* b_l0  = (const float*)d_in[5];
    const float* w_r0  = (const float*)d_in[6];
    const float* w_l1  = (const float*)d_in[7];
    const float* b_l1  = (const float*)d_in[8];
    const float* w_r1  = (const float*)d_in[9];
    const float* w_ih  = (const float*)d_in[10];
    // d_in[11] = w_hh: dead (h0 = 0)
    const float* b_ih  = (const float*)d_in[12];
    const float* b_hh  = (const float*)d_in[13];
    const float* wc0   = (const float*)d_in[14];
    const float* bc0   = (const float*)d_in[15];
    const float* wc1   = (const float*)d_in[16];
    const float* bc1   = (const float*)d_in[17];
    const float* wc2   = (const float*)d_in[18];
    const float* bc2   = (const float*)d_in[19];

    const int N = in_sizes[0] / 128;
    const int E = in_sizes[1] / 2;
    const int B = in_sizes[2];
    const int nbuckets = (N + BNODES - 1) >> BSHIFT;

    char* ws = (char*)d_ws;
    size_t off = 0;
    auto alloc = [&](size_t bytes) -> void* {
        void* p = ws + off; off += (bytes + 255) & ~(size_t)255; return p;
    };
    float* arenaA   = (float*)alloc((size_t)N*128*4);   // mean0 -> mean1 -> gates
    float* arenaB   = (float*)alloc((size_t)N*128*4);   // pairs -> h -> lstm/z0/z1
    float* ue       = (float*)alloc((size_t)B*128*4);
    __half* xh      = (__half*)alloc((size_t)N*128*2);
    // zero-init region (one memset): degi, flag, ucnt
    int*   degi     = (int*)  alloc((size_t)N*4);
    int*   flag     = (int*)  alloc((size_t)N*4);
    int*   ucnt     = (int*)  alloc(256);
    char*  zero_end = ws + off;
    int*   row_start= (int*)  alloc((size_t)(N+1)*4);
    int*   chunksum = (int*)  alloc(1024*4);
    int*   bcur     = (int*)  alloc((size_t)nbuckets*4);
    int*   col_idx  = (int*)  alloc((size_t)E*4);
    int*   ulist    = (int*)  alloc((size_t)B*4);
    short* wt0h     = (short*)alloc(128*256*2);
    short* wt0l     = (short*)alloc(128*256*2);
    float* wt1      = (float*)alloc(256*128*4);
    float* wtg      = (float*)alloc(256*384*4);
    float* bsum     = (float*)alloc(384*4);
    float* ohtab    = (float*)alloc(5*384*4);
    float* wtc0     = (float*)alloc(256*128*4);
    float* wtc1     = (float*)alloc(128*64*4);

    int2*  pairs = (int2*)arenaB;                // consumed by fill_bucket before h is written
    float* mean0 = arenaA;
    float* h     = arenaB;
    float* mean1 = arenaA;
    float* gates = arenaA;
    float* lstm  = arenaB;
    float* z0    = arenaB + (size_t)B*128;
    float* z1    = arenaB + (size_t)B*128*2;

    hipMemsetAsync(degi, 0, (size_t)(zero_end - (char*)degi), stream);

    const int gE = (E + 255)/256;
    const int nchunk = (N + SCAN_CHUNK - 1)/SCAN_CHUNK;

    count_deg<<<gE, 256, 0, stream>>>(edge + E, E, degi);
    scan1<<<nchunk, 256, 0, stream>>>(degi, N, row_start, chunksum);
    scan2<<<1, 256, 0, stream>>>(chunksum, nchunk);
    scan3<<<(N + 255)/256, 256, 0, stream>>>(row_start, chunksum, N, E);
    init_bcur<<<(nbuckets + 255)/256, 256, 0, stream>>>(row_start, bcur, nbuckets, N);
    bin_edges_priv<<<(E + ECHUNK - 1)/ECHUNK, 256, 0, stream>>>(edge, edge + E, E, nbuckets, bcur, pairs);
    fill_bucket<<<nbuckets, 256, 0, stream>>>(pairs, row_start, col_idx, N);
    flag_users<<<(B + 255)/256, 256, 0, stream>>>(uid, B, flag);
    compact_flags<<<(N + 255)/256, 256, 0, stream>>>(flag, N, ulist, ucnt);

    convert_fp16<<<(N*128/8 + 255)/256, 256, 0, stream>>>(x, xh, (long)N*128/8);
    prep_all<<<802, 256, 0, stream>>>(w_l0, w_r0, w_l1, w_r1, wc0, wc1, w_ih, b_ih, b_hh,
                                      wt0h, wt0l, wt1, wtc0, wtc1, wtg, bsum, ohtab);

    // layer 0: mean over all nodes (fp16 gather), then h = relu([mean0|x] @ wt0^T + b_l0) via MFMA
    aggregate_h16<<<(N + 3)/4, 256, 0, stream>>>(xh, row_start, col_idx, mean0, N);
    gemm0_mfma<<<(N + 63)/64, 256, 0, stream>>>(mean0, x, wt0h, wt0l, b_l0, h, N);

    // layer 1: aggregation + dense only for user nodes (compacted list, fp32 gather)
    aggregate_k<<<(B + 3)/4, 256, 0, stream>>>(h, row_start, col_idx, ulist, ucnt, mean1, N);
    GemmArgs gu { mean1, h, uid, wt1, 128, b_l1, nullptr, nullptr, ue, 128, B };
    gemm_k<1><<<dim3(B/64, 1), THREADS, 0, stream>>>(gu);

    // LSTM gates (i,g,o only) + activation
    GemmArgs gg { ue, x, uid, wtg, 384, bsum, ohtab, roles, gates, 384, B };
    gemm_k<2><<<dim3(B/64, 3), THREADS, 0, stream>>>(gg);
    lstm_act<<<(B*128 + 255)/256, 256, 0, stream>>>(gates, lstm, B);

    // classifier MLP
    GemmArgs gz0 { ue, lstm, nullptr, wtc0, 128, bc0, nullptr, nullptr, z0, 128, B };
    gemm_k<3><<<dim3(B/64, 1), THREADS, 0, stream>>>(gz0);
    GemmArgs gz1 { z0, nullptr, nullptr, wtc1, 64, bc1, nullptr, nullptr, z1, 64, B };
    gemm_k<4><<<dim3(B/64, 1), THREADS, 0, stream>>>(gz1);
    out_k<<<(B*8 + 255)/256, 256, 0, stream>>>(z1, wc2, bc2, (float*)d_out, B);

    (void)n_in; (void)out_size; (void)ws_size;
}

// Round 7
// 486.519 us; speedup vs baseline: 2.9028x; 1.1166x over previous
//
#include <hip/hip_runtime.h>
#include <hip/hip_fp16.h>
#include <math.h>

#define THREADS 256
#define KC 32
#define BSHIFT 9          // 512 nodes per bucket
#define BNODES (1 << BSHIFT)
#define NB_MAX 256        // max buckets (N<=131072)
#define ECHUNK 4096       // edges per block in binning kernels

__device__ __forceinline__ float clipf(float v){ return fminf(fmaxf(v, -10.f), 10.f); }

typedef __attribute__((ext_vector_type(8))) short bf16x8;
typedef __attribute__((ext_vector_type(4))) float f32x4;

// split fp32 into bf16 hi + bf16 lo (3-term split-GEMM decomposition)
__device__ __forceinline__ void split_bf16(float f, short& hi, short& lo){
    union { float f; unsigned u; } a; a.f = f;
    unsigned r = (a.u + 0x7FFFu + ((a.u >> 16) & 1u)) & 0xFFFF0000u;
    hi = (short)(r >> 16);
    union { unsigned u; float f; } b; b.u = r;
    float rem = f - b.f;
    union { float f; unsigned u; } c; c.f = rem;
    unsigned r2 = c.u + 0x7FFFu + ((c.u >> 16) & 1u);
    lo = (short)(r2 >> 16);
}

// ---------------------------------------------------------------- CSR build (bucket-first, no per-node global histogram)
// pass A: bucket histogram via LDS privatization
__global__ __launch_bounds__(256) void hist_b(const int* __restrict__ dstv, int E, int nbuckets, int* __restrict__ bcnt){
    __shared__ int h[NB_MAX];
    int b0 = blockIdx.x * ECHUNK;
    int b1 = min(b0 + ECHUNK, E);
    for (int i = threadIdx.x; i < nbuckets; i += 256) h[i] = 0;
    __syncthreads();
    for (int i = b0 + threadIdx.x; i < b1; i += 256)
        atomicAdd(&h[dstv[i] >> BSHIFT], 1);
    __syncthreads();
    for (int i = threadIdx.x; i < nbuckets; i += 256){
        int c = h[i];
        if (c) atomicAdd(&bcnt[i], c);
    }
}

// single block: exclusive scan of nb<=256 bucket counts -> boffs, bcur; row_start[N]=E
__global__ __launch_bounds__(256) void scan_b(const int* __restrict__ bcnt, int nb, int E, int N,
                                              int* __restrict__ boffs, int* __restrict__ bcur, int* __restrict__ row_start){
    __shared__ int sh[256];
    int t = threadIdx.x;
    int v = (t < nb) ? bcnt[t] : 0;
    sh[t] = v; __syncthreads();
    for (int off = 1; off < 256; off <<= 1){
        int u = (t >= off) ? sh[t-off] : 0;
        __syncthreads();
        sh[t] += u;
        __syncthreads();
    }
    int ex = sh[t] - v;
    if (t < nb){ boffs[t] = ex; bcur[t] = ex; }
    if (t == 0){ boffs[nb] = E; row_start[N] = E; }
}

// pass B (privatized): each block bins an ECHUNK-edge slice.
__global__ __launch_bounds__(256) void bin_edges_priv(const int* __restrict__ srcv, const int* __restrict__ dstv, int E,
                                                      int nbuckets, int* __restrict__ bcur, int2* __restrict__ pairs){
    __shared__ int cnt[NB_MAX];
    __shared__ int base[NB_MAX];
    int b0 = blockIdx.x * ECHUNK;
    int b1 = min(b0 + ECHUNK, E);
    for (int i = threadIdx.x; i < nbuckets; i += 256) cnt[i] = 0;
    __syncthreads();
    for (int i = b0 + threadIdx.x; i < b1; i += 256)
        atomicAdd(&cnt[dstv[i] >> BSHIFT], 1);
    __syncthreads();
    for (int i = threadIdx.x; i < nbuckets; i += 256){
        int c = cnt[i];
        base[i] = c ? atomicAdd(&bcur[i], c) : 0;
    }
    __syncthreads();
    for (int i = threadIdx.x; i < nbuckets; i += 256) cnt[i] = 0;
    __syncthreads();
    for (int i = b0 + threadIdx.x; i < b1; i += 256){
        int d = dstv[i];
        int bk = d >> BSHIFT;
        int loc = atomicAdd(&cnt[bk], 1);
        pairs[base[bk] + loc] = make_int2(d, srcv[i]);
    }
}

// pass C: one wg per bucket. LDS degree count -> 512-wide LDS exclusive scan ->
// writes row_start slice -> LDS-cursor scatter of col_idx (L2-hot window).
__global__ __launch_bounds__(256) void fill_bucket2(const int2* __restrict__ pairs, const int* __restrict__ boffs,
                                                    int* __restrict__ row_start, int* __restrict__ col_idx, int N){
    __shared__ int cur[BNODES];
    __shared__ int sh[256];
    int b  = blockIdx.x;
    int n0 = b << BSHIFT;
    int nn = min(BNODES, N - n0);
    int s = boffs[b], e = boffs[b+1];
    int t = threadIdx.x;
    cur[2*t]   = 0;
    cur[2*t+1] = 0;
    __syncthreads();
    for (int i = s + t; i < e; i += 256)
        atomicAdd(&cur[pairs[i].x - n0], 1);
    __syncthreads();
    int c0 = cur[2*t], c1 = cur[2*t+1];
    int s2 = c0 + c1;
    sh[t] = s2; __syncthreads();
    for (int off = 1; off < 256; off <<= 1){
        int u = (t >= off) ? sh[t-off] : 0;
        __syncthreads();
        sh[t] += u;
        __syncthreads();
    }
    int ex = sh[t] - s2;
    __syncthreads();
    cur[2*t]   = s + ex;
    cur[2*t+1] = s + ex + c0;
    __syncthreads();
    for (int i = t; i < nn; i += 256) row_start[n0 + i] = cur[i];
    __syncthreads();
    for (int i = s + t; i < e; i += 256){
        int2 p = pairs[i];
        int loc = atomicAdd(&cur[p.x - n0], 1);
        col_idx[loc] = p.y;
    }
}

__global__ __launch_bounds__(256) void flag_users(const int* __restrict__ uid, int B, int* __restrict__ flag){
    int i = blockIdx.x*256 + threadIdx.x;
    if (i < B) flag[uid[i]] = 1;
}

__global__ __launch_bounds__(256) void compact_flags(const int* __restrict__ flag, int N, int* __restrict__ list, int* __restrict__ cnt){
    int i = blockIdx.x*256 + threadIdx.x;
    if (i < N && flag[i]){ int p = atomicAdd(cnt, 1); list[p] = i; }
}

// ---------------------------------------------------------------- x -> fp16 copy (for layer-0 gather)
__global__ __launch_bounds__(256) void convert_fp16(const float* __restrict__ in, __half* __restrict__ out, long n8){
    long t = (long)blockIdx.x*256 + threadIdx.x;
    if (t >= n8) return;
    long i = t*8;
    float4 a = *(const float4*)(in + i);
    float4 b = *(const float4*)(in + i + 4);
    union { __half2 h[4]; float4 f; } u;
    u.h[0] = __floats2half2_rn(a.x, a.y);
    u.h[1] = __floats2half2_rn(a.z, a.w);
    u.h[2] = __floats2half2_rn(b.x, b.y);
    u.h[3] = __floats2half2_rn(b.z, b.w);
    *(float4*)(out + i) = u.f;
}

// ---------------------------------------------------------------- fused weight prep (one launch)
__global__ __launch_bounds__(256) void prep_all(const float* __restrict__ w_l0, const float* __restrict__ w_r0,
                                                const float* __restrict__ w_l1, const float* __restrict__ w_r1,
                                                const float* __restrict__ wc0,  const float* __restrict__ wc1,
                                                const float* __restrict__ w_ih, const float* __restrict__ b_ih,
                                                const float* __restrict__ b_hh,
                                                short* __restrict__ wt0h, short* __restrict__ wt0l,
                                                float* __restrict__ wt1, float* __restrict__ wtc0,
                                                float* __restrict__ wtc1, float* __restrict__ wtg,
                                                float* __restrict__ bsum, float* __restrict__ ohtab){
    int idx = blockIdx.x*256 + threadIdx.x;
    if (idx < 32768){
        int n = idx >> 8, k = idx & 255;
        float f = (k < 128) ? w_l0[n*128 + k] : w_r0[n*128 + (k - 128)];
        short h, l; split_bf16(f, h, l);
        wt0h[idx] = h; wt0l[idx] = l;
    } else if (idx < 65536){
        int i = idx - 32768;
        int which = i >> 14, e = i & 16383;
        int j = e >> 7, k = e & 127;
        const float* w = which ? w_r1 : w_l1;
        wt1[(which*128 + k)*128 + j] = w[j*128 + k];
    } else if (idx < 98304){
        int i = idx - 65536;
        int j = i >> 8, k = i & 255;
        wtc0[k*128 + j] = wc0[j*256 + k];
    } else if (idx < 106496){
        int i = idx - 98304;
        int j = i >> 7, k = i & 127;
        wtc1[k*64 + j] = wc1[j*128 + k];
    } else if (idx < 204800){
        int i = idx - 106496;
        int jj = i % 384, k = i / 384;
        int j = jj + ((jj >= 128) ? 128 : 0);
        wtg[k*384 + jj] = w_ih[j*261 + k];
    } else if (idx < 205184){
        int jj = idx - 204800;
        int j = jj + ((jj >= 128) ? 128 : 0);
        bsum[jj] = b_ih[j] + b_hh[j];
        for (int r = 0; r < 5; ++r) ohtab[r*384 + jj] = w_ih[j*261 + 256 + r];
    }
}

// ---------------------------------------------------------------- layer-0 mean aggregation (fp16 gather, fp32 accum)
__device__ __forceinline__ void accumh(float4& a0, float4& a1, float4 v){
    const __half2* h = (const __half2*)&v;
    float2 f0 = __half22float2(h[0]);
    float2 f1 = __half22float2(h[1]);
    float2 f2 = __half22float2(h[2]);
    float2 f3 = __half22float2(h[3]);
    a0.x += f0.x; a0.y += f0.y; a0.z += f1.x; a0.w += f1.y;
    a1.x += f2.x; a1.y += f2.y; a1.z += f3.x; a1.w += f3.y;
}

__global__ __launch_bounds__(256) void aggregate_h16(const __half* __restrict__ feat, const int* __restrict__ row_start,
                                                     const int* __restrict__ col_idx,
                                                     float* __restrict__ outmean, int N){
    int wave = (blockIdx.x*256 + threadIdx.x) >> 6;
    if (wave >= N) return;
    int lane = threadIdx.x & 63;
    int g  = lane >> 4;
    int sl = lane & 15;
    int s = row_start[wave], e = row_start[wave+1];
    const float4* f16 = (const float4*)feat;
    float4 a0 = make_float4(0.f,0.f,0.f,0.f);
    float4 a1 = make_float4(0.f,0.f,0.f,0.f);
    int i = s + g;
    for (; i + 12 < e; i += 16){
        int s0 = col_idx[i];
        int s1 = col_idx[i+4];
        int s2 = col_idx[i+8];
        int s3 = col_idx[i+12];
        float4 v0 = f16[(long)s0*16 + sl];
        float4 v1 = f16[(long)s1*16 + sl];
        float4 v2 = f16[(long)s2*16 + sl];
        float4 v3 = f16[(long)s3*16 + sl];
        accumh(a0, a1, v0);
        accumh(a0, a1, v1);
        accumh(a0, a1, v2);
        accumh(a0, a1, v3);
    }
    for (; i < e; i += 4){
        float4 v0 = f16[(long)col_idx[i]*16 + sl];
        accumh(a0, a1, v0);
    }
    a0.x += __shfl_xor(a0.x, 16, 64); a0.x += __shfl_xor(a0.x, 32, 64);
    a0.y += __shfl_xor(a0.y, 16, 64); a0.y += __shfl_xor(a0.y, 32, 64);
    a0.z += __shfl_xor(a0.z, 16, 64); a0.z += __shfl_xor(a0.z, 32, 64);
    a0.w += __shfl_xor(a0.w, 16, 64); a0.w += __shfl_xor(a0.w, 32, 64);
    a1.x += __shfl_xor(a1.x, 16, 64); a1.x += __shfl_xor(a1.x, 32, 64);
    a1.y += __shfl_xor(a1.y, 16, 64); a1.y += __shfl_xor(a1.y, 32, 64);
    a1.z += __shfl_xor(a1.z, 16, 64); a1.z += __shfl_xor(a1.z, 32, 64);
    a1.w += __shfl_xor(a1.w, 16, 64); a1.w += __shfl_xor(a1.w, 32, 64);
    if (g == 0){
        float inv = 1.f / fmaxf((float)(e - s), 1.f);
        a0.x *= inv; a0.y *= inv; a0.z *= inv; a0.w *= inv;
        a1.x *= inv; a1.y *= inv; a1.z *= inv; a1.w *= inv;
        float4* om = (float4*)(outmean + (long)wave*128 + sl*8);
        om[0] = a0;
        om[1] = a1;
    }
}

// ---------------------------------------------------------------- layer-1 mean aggregation (fp32 gather, compacted list)
__global__ __launch_bounds__(256) void aggregate_k(const float* __restrict__ feat, const int* __restrict__ row_start,
                                                   const int* __restrict__ col_idx,
                                                   const int* __restrict__ list, const int* __restrict__ cnt,
                                                   float* __restrict__ outmean, int N){
    int wave = (blockIdx.x*256 + threadIdx.x) >> 6;
    int lane = threadIdx.x & 63;
    if (wave >= *cnt) return;
    int node = list[wave];
    int s = row_start[node], e = row_start[node+1];
    int half = lane >> 5;
    int sl   = lane & 31;
    const float4* feat4 = (const float4*)feat;
    float4 a0 = make_float4(0.f,0.f,0.f,0.f);
    float4 a1 = make_float4(0.f,0.f,0.f,0.f);
    int i = s + half;
    for (; i + 6 < e; i += 8){
        int s0 = col_idx[i];
        int s1 = col_idx[i+2];
        int s2 = col_idx[i+4];
        int s3 = col_idx[i+6];
        float4 v0 = feat4[(long)s0*32 + sl];
        float4 v1 = feat4[(long)s1*32 + sl];
        float4 v2 = feat4[(long)s2*32 + sl];
        float4 v3 = feat4[(long)s3*32 + sl];
        a0.x += v0.x + v1.x; a0.y += v0.y + v1.y; a0.z += v0.z + v1.z; a0.w += v0.w + v1.w;
        a1.x += v2.x + v3.x; a1.y += v2.y + v3.y; a1.z += v2.z + v3.z; a1.w += v2.w + v3.w;
    }
    for (; i < e; i += 2){
        int s0 = col_idx[i];
        float4 v0 = feat4[(long)s0*32 + sl];
        a0.x += v0.x; a0.y += v0.y; a0.z += v0.z; a0.w += v0.w;
    }
    a0.x += a1.x; a0.y += a1.y; a0.z += a1.z; a0.w += a1.w;
    a0.x += __shfl_xor(a0.x, 32, 64);
    a0.y += __shfl_xor(a0.y, 32, 64);
    a0.z += __shfl_xor(a0.z, 32, 64);
    a0.w += __shfl_xor(a0.w, 32, 64);
    if (half == 0){
        float inv = 1.f / fmaxf((float)(e - s), 1.f);
        a0.x *= inv; a0.y *= inv; a0.z *= inv; a0.w *= inv;
        ((float4*)outmean)[(long)node*32 + sl] = a0;
    }
}

// ---------------------------------------------------------------- MODE-0 GEMM via split-bf16 MFMA
#define AROW 40
__global__ __launch_bounds__(256) void gemm0_mfma(const float* __restrict__ mean0, const float* __restrict__ x,
                                                  const short* __restrict__ wh, const short* __restrict__ wl,
                                                  const float* __restrict__ bias, float* __restrict__ out, int M){
    __shared__ __align__(16) short Ah[64*AROW];
    __shared__ __align__(16) short Al[64*AROW];
    __shared__ __align__(16) short Wh[128*AROW];
    __shared__ __align__(16) short Wl[128*AROW];

    const int tid  = threadIdx.x;
    const int row0 = blockIdx.x * 64;
    const int wave = tid >> 6, lane = tid & 63;
    const int lm = lane & 15, quad = lane >> 4;

    f32x4 acc[8];
    #pragma unroll
    for (int t = 0; t < 8; ++t) acc[t] = (f32x4){0.f, 0.f, 0.f, 0.f};

    for (int ko = 0; ko < 256; ko += KC){
        const float* Asrc = (ko < 128) ? (mean0 + ko) : (x + (ko - 128));
        #pragma unroll
        for (int it = 0; it < 2; ++it){
            int idx = it*256 + tid;
            int r = idx >> 3, k4 = idx & 7;
            int grow = row0 + r; if (grow >= M) grow = M - 1;
            float4 v = *(const float4*)(Asrc + (long)grow*128 + k4*4);
            union { short s[4]; int2 p; } ph, pl;
            split_bf16(v.x, ph.s[0], pl.s[0]);
            split_bf16(v.y, ph.s[1], pl.s[1]);
            split_bf16(v.z, ph.s[2], pl.s[2]);
            split_bf16(v.w, ph.s[3], pl.s[3]);
            *(int2*)&Ah[r*AROW + k4*4] = ph.p;
            *(int2*)&Al[r*AROW + k4*4] = pl.p;
        }
        #pragma unroll
        for (int it = 0; it < 2; ++it){
            int idx = it*256 + tid;
            int n = idx >> 2, q = idx & 3;
            int4 vh = *(const int4*)(wh + (long)n*256 + ko + q*8);
            *(int4*)&Wh[n*AROW + q*8] = vh;
            int4 vlo = *(const int4*)(wl + (long)n*256 + ko + q*8);
            *(int4*)&Wl[n*AROW + q*8] = vlo;
        }
        __syncthreads();

        bf16x8 ah = *(const bf16x8*)&Ah[(wave*16 + lm)*AROW + quad*8];
        bf16x8 al = *(const bf16x8*)&Al[(wave*16 + lm)*AROW + quad*8];
        #pragma unroll
        for (int t = 0; t < 8; ++t){
            bf16x8 bh = *(const bf16x8*)&Wh[(t*16 + lm)*AROW + quad*8];
            bf16x8 bl = *(const bf16x8*)&Wl[(t*16 + lm)*AROW + quad*8];
            acc[t] = __builtin_amdgcn_mfma_f32_16x16x32_bf16(ah, bh, acc[t], 0, 0, 0);
            acc[t] = __builtin_amdgcn_mfma_f32_16x16x32_bf16(ah, bl, acc[t], 0, 0, 0);
            acc[t] = __builtin_amdgcn_mfma_f32_16x16x32_bf16(al, bh, acc[t], 0, 0, 0);
        }
        __syncthreads();
    }

    #pragma unroll
    for (int t = 0; t < 8; ++t){
        int col = t*16 + lm;
        float b = bias[col];
        #pragma unroll
        for (int r = 0; r < 4; ++r){
            int row = row0 + wave*16 + quad*4 + r;
            if (row < M) out[(long)row*128 + col] = fmaxf(acc[t][r] + b, 0.f);
        }
    }
}

// ---------------------------------------------------------------- generic fp32 GEMM (modes 1-4)
struct GemmArgs {
    const float* a0; const float* a1; const int* g;
    const float* wt; int ncolsW;
    const float* bias; const float* ohtab; const int* roles;
    float* out; int ncolsOut; int M;
};

template<int MODE>
__device__ __forceinline__ float4 load_a(const GemmArgs& A, int row, int k){
    if constexpr (MODE == 1){
        int node = A.g[row];
        const float* p = (k < 128) ? A.a0 + (long)node*128 + k : A.a1 + (long)node*128 + (k-128);
        return *(const float4*)p;
    } else if constexpr (MODE == 2){
        if (k < 128) return *(const float4*)(A.a0 + (long)row*128 + k);
        int node = A.g[row];
        float4 v = *(const float4*)(A.a1 + (long)node*128 + (k-128));
        v.x = clipf(v.x); v.y = clipf(v.y); v.z = clipf(v.z); v.w = clipf(v.w);
        return v;
    } else if constexpr (MODE == 4){
        return *(const float4*)(A.a0 + (long)row*128 + k);
    } else {
        const float* p = (k < 128) ? A.a0 + (long)row*128 + k : A.a1 + (long)row*128 + (k-128);
        return *(const float4*)p;
    }
}

template<int MODE>
__global__ __launch_bounds__(THREADS) void gemm_k(GemmArgs A){
    constexpr int BM = 64;
    constexpr int BN = (MODE == 4) ? 64 : 128;
    constexpr int TN = 4;
    constexpr int CT = BN / TN;
    constexpr int RT = THREADS / CT;
    constexpr int TM = BM / RT;
    constexpr int KTOT = (MODE == 4) ? 128 : 256;
    constexpr int AST = BM + 4;

    __shared__ __align__(16) float As[KC][AST];
    __shared__ __align__(16) float Ws[KC][BN];

    const int tid  = threadIdx.x;
    const int row0 = blockIdx.x * BM;
    const int col0 = blockIdx.y * BN;
    const int c  = tid % CT;
    const int rt = tid / CT;

    float acc[TM][TN];
    #pragma unroll
    for (int i = 0; i < TM; ++i)
        #pragma unroll
        for (int j = 0; j < TN; ++j) acc[i][j] = 0.f;

    for (int ko = 0; ko < KTOT; ko += KC){
        #pragma unroll
        for (int it = 0; it < (BM*KC/4)/THREADS; ++it){
            int idx = it*THREADS + tid;
            int r  = idx >> 3;
            int k4 = idx & 7;
            int grow = row0 + r; if (grow >= A.M) grow = A.M - 1;
            float4 v = load_a<MODE>(A, grow, ko + k4*4);
            As[k4*4+0][r] = v.x;
            As[k4*4+1][r] = v.y;
            As[k4*4+2][r] = v.z;
            As[k4*4+3][r] = v.w;
        }
        #pragma unroll
        for (int it = 0; it < (KC*BN/4)/THREADS; ++it){
            int idx = it*THREADS + tid;
            int kk = idx / (BN/4);
            int c4 = idx % (BN/4);
            float4 v = *(const float4*)&A.wt[(long)(ko+kk)*A.ncolsW + col0 + c4*4];
            *(float4*)&Ws[kk][c4*4] = v;
        }
        __syncthreads();
        #pragma unroll
        for (int kk = 0; kk < KC; ++kk){
            float4 wv = *(const float4*)&Ws[kk][c*4];
            float w[TN] = {wv.x, wv.y, wv.z, wv.w};
            float a[TM];
            #pragma unroll
            for (int q = 0; q < TM/4; ++q){
                float4 av = *(const float4*)&As[kk][rt*TM + q*4];
                a[q*4+0] = av.x; a[q*4+1] = av.y; a[q*4+2] = av.z; a[q*4+3] = av.w;
            }
            #pragma unroll
            for (int i = 0; i < TM; ++i)
                #pragma unroll
                for (int j = 0; j < TN; ++j) acc[i][j] = fmaf(a[i], w[j], acc[i][j]);
        }
        __syncthreads();
    }

    #pragma unroll
    for (int i = 0; i < TM; ++i){
        int grow = row0 + rt*TM + i;
        if (grow >= A.M) continue;
        #pragma unroll
        for (int j = 0; j < TN; ++j){
            int gcol = col0 + c*4 + j;
            float v = acc[i][j];
            if constexpr (MODE == 0)      v = fmaxf(v + A.bias[gcol], 0.f);
            else if constexpr (MODE == 1) v = clipf(v + A.bias[gcol]);
            else if constexpr (MODE == 2) v = v + A.bias[gcol] + A.ohtab[A.roles[grow]*384 + gcol];
            else                          v = fmaxf(v + A.bias[gcol], 0.f);
            A.out[(long)grow*A.ncolsOut + gcol] = v;
        }
    }
}

// ---------------------------------------------------------------- LSTM activation (f-gate dead, c0=0)
__global__ __launch_bounds__(256) void lstm_act(const float* __restrict__ gates, float* __restrict__ lstm, int B){
    int idx = blockIdx.x*256 + threadIdx.x;
    if (idx >= B*128) return;
    int b = idx >> 7, j = idx & 127;
    const float* gr = gates + (long)b*384;
    float i_ = gr[j], g_ = gr[128 + j], o_ = gr[256 + j];
    float si = 1.f/(1.f + expf(-i_));
    float c  = si * tanhf(g_);
    float so = 1.f/(1.f + expf(-o_));
    lstm[idx] = clipf(so * tanhf(c));
}

// ---------------------------------------------------------------- final tiny GEMM [B,64]@[64,5]
__global__ __launch_bounds__(256) void out_k(const float* __restrict__ z1, const float* __restrict__ wc2, const float* __restrict__ bc2,
                                             float* __restrict__ out, int B){
    int idx = blockIdx.x*256 + threadIdx.x;
    int b = idx >> 3, r = idx & 7;
    if (b >= B || r >= 5) return;
    const float* zr = z1 + (long)b*64;
    const float* wr = wc2 + r*64;
    float acc = bc2[r];
    #pragma unroll 16
    for (int k = 0; k < 64; ++k) acc = fmaf(zr[k], wr[k], acc);
    out[b*5 + r] = acc;
}

// ----------------------------------------------------------------
extern "C" void kernel_launch(void* const* d_in, const int* in_sizes, int n_in,
                              void* d_out, int out_size, void* d_ws, size_t ws_size,
                              hipStream_t stream){
    const float* x     = (const float*)d_in[0];
    const int*   edge  = (const int*)  d_in[1];
    const int*   uid   = (const int*)  d_in[2];
    const int*   roles = (const int*)  d_in[3];
    const float* w_l0  = (const float*)d_in[4];
    const float* b_l0  = (const float*)d_in[5];
    const float* w_r0  = (const float*)d_in[6];
    const float* w_l1  = (const float*)d_in[7];
    const float* b_l1  = (const float*)d_in[8];
    const float* w_r1  = (const float*)d_in[9];
    const float* w_ih  = (const float*)d_in[10];
    // d_in[11] = w_hh: dead (h0 = 0)
    const float* b_ih  = (const float*)d_in[12];
    const float* b_hh  = (const float*)d_in[13];
    const float* wc0   = (const float*)d_in[14];
    const float* bc0   = (const float*)d_in[15];
    const float* wc1   = (const float*)d_in[16];
    const float* bc1   = (const float*)d_in[17];
    const float* wc2   = (const float*)d_in[18];
    const float* bc2   = (const float*)d_in[19];

    const int N = in_sizes[0] / 128;
    const int E = in_sizes[1] / 2;
    const int B = in_sizes[2];
    const int nbuckets = (N + BNODES - 1) >> BSHIFT;

    char* ws = (char*)d_ws;
    size_t off = 0;
    auto alloc = [&](size_t bytes) -> void* {
        void* p = ws + off; off += (bytes + 255) & ~(size_t)255; return p;
    };
    float* arenaA   = (float*)alloc((size_t)N*128*4);   // mean0 -> mean1 -> gates
    float* arenaB   = (float*)alloc((size_t)N*128*4);   // pairs -> h -> lstm/z0/z1
    float* ue       = (float*)alloc((size_t)B*128*4);
    __half* xh      = (__half*)alloc((size_t)N*128*2);
    // zero-init region (one memset): flag, ucnt, bcnt
    int*   flag     = (int*)  alloc((size_t)N*4);
    int*   ucnt     = (int*)  alloc(256);
    int*   bcnt     = (int*)  alloc(NB_MAX*4);
    char*  zero_end = ws + off;
    int*   row_start= (int*)  alloc((size_t)(N+1)*4);
    int*   boffs    = (int*)  alloc((size_t)(NB_MAX+1)*4);
    int*   bcur     = (int*)  alloc((size_t)NB_MAX*4);
    int*   col_idx  = (int*)  alloc((size_t)E*4);
    int*   ulist    = (int*)  alloc((size_t)B*4);
    short* wt0h     = (short*)alloc(128*256*2);
    short* wt0l     = (short*)alloc(128*256*2);
    float* wt1      = (float*)alloc(256*128*4);
    float* wtg      = (float*)alloc(256*384*4);
    float* bsum     = (float*)alloc(384*4);
    float* ohtab    = (float*)alloc(5*384*4);
    float* wtc0     = (float*)alloc(256*128*4);
    float* wtc1     = (float*)alloc(128*64*4);

    int2*  pairs = (int2*)arenaB;                // consumed by fill_bucket2 before h is written
    float* mean0 = arenaA;
    float* h     = arenaB;
    float* mean1 = arenaA;
    float* gates = arenaA;
    float* lstm  = arenaB;
    float* z0    = arenaB + (size_t)B*128;
    float* z1    = arenaB + (size_t)B*128*2;

    hipMemsetAsync(flag, 0, (size_t)(zero_end - (char*)flag), stream);

    const int gEC = (E + ECHUNK - 1)/ECHUNK;

    hist_b<<<gEC, 256, 0, stream>>>(edge + E, E, nbuckets, bcnt);
    scan_b<<<1, 256, 0, stream>>>(bcnt, nbuckets, E, N, boffs, bcur, row_start);
    bin_edges_priv<<<gEC, 256, 0, stream>>>(edge, edge + E, E, nbuckets, bcur, pairs);
    fill_bucket2<<<nbuckets, 256, 0, stream>>>(pairs, boffs, row_start, col_idx, N);
    flag_users<<<(B + 255)/256, 256, 0, stream>>>(uid, B, flag);
    compact_flags<<<(N + 255)/256, 256, 0, stream>>>(flag, N, ulist, ucnt);

    convert_fp16<<<(N*128/8 + 255)/256, 256, 0, stream>>>(x, xh, (long)N*128/8);
    prep_all<<<802, 256, 0, stream>>>(w_l0, w_r0, w_l1, w_r1, wc0, wc1, w_ih, b_ih, b_hh,
                                      wt0h, wt0l, wt1, wtc0, wtc1, wtg, bsum, ohtab);

    // layer 0: mean over all nodes (fp16 gather), then h = relu([mean0|x] @ wt0^T + b_l0) via MFMA
    aggregate_h16<<<(N + 3)/4, 256, 0, stream>>>(xh, row_start, col_idx, mean0, N);
    gemm0_mfma<<<(N + 63)/64, 256, 0, stream>>>(mean0, x, wt0h, wt0l, b_l0, h, N);

    // layer 1: aggregation + dense only for user nodes (compacted list, fp32 gather)
    aggregate_k<<<(B + 3)/4, 256, 0, stream>>>(h, row_start, col_idx, ulist, ucnt, mean1, N);
    GemmArgs gu { mean1, h, uid, wt1, 128, b_l1, nullptr, nullptr, ue, 128, B };
    gemm_k<1><<<dim3(B/64, 1), THREADS, 0, stream>>>(gu);

    // LSTM gates (i,g,o only) + activation
    GemmArgs gg { ue, x, uid, wtg, 384, bsum, ohtab, roles, gates, 384, B };
    gemm_k<2><<<dim3(B/64, 3), THREADS, 0, stream>>>(gg);
    lstm_act<<<(B*128 + 255)/256, 256, 0, stream>>>(gates, lstm, B);

    // classifier MLP
    GemmArgs gz0 { ue, lstm, nullptr, wtc0, 128, bc0, nullptr, nullptr, z0, 128, B };
    gemm_k<3><<<dim3(B/64, 1), THREADS, 0, stream>>>(gz0);
    GemmArgs gz1 { z0, nullptr, nullptr, wtc1, 64, bc1, nullptr, nullptr, z1, 64, B };
    gemm_k<4><<<dim3(B/64, 1), THREADS, 0, stream>>>(gz1);
    out_k<<<(B*8 + 255)/256, 256, 0, stream>>>(z1, wc2, bc2, (float*)d_out, B);

    (void)n_in; (void)out_size; (void)ws_size;
}

// Round 8
// 452.980 us; speedup vs baseline: 3.1178x; 1.0740x over previous
//
#include <hip/hip_runtime.h>
#include <hip/hip_fp16.h>
#include <math.h>

#define THREADS 256
#define KC 32
#define BSHIFT 9          // 512 nodes per bucket
#define BNODES (1 << BSHIFT)
#define NB_MAX 256        // max buckets (N<=131072)
#define ECHUNK 4096       // edges per block in binning kernels

__device__ __forceinline__ float clipf(float v){ return fminf(fmaxf(v, -10.f), 10.f); }

typedef __attribute__((ext_vector_type(8))) short bf16x8;
typedef __attribute__((ext_vector_type(4))) float f32x4;

// split fp32 into bf16 hi + bf16 lo (3-term split-GEMM decomposition)
__device__ __forceinline__ void split_bf16(float f, short& hi, short& lo){
    union { float f; unsigned u; } a; a.f = f;
    unsigned r = (a.u + 0x7FFFu + ((a.u >> 16) & 1u)) & 0xFFFF0000u;
    hi = (short)(r >> 16);
    union { unsigned u; float f; } b; b.u = r;
    float rem = f - b.f;
    union { float f; unsigned u; } c; c.f = rem;
    unsigned r2 = c.u + 0x7FFFu + ((c.u >> 16) & 1u);
    lo = (short)(r2 >> 16);
}

// ---------------------------------------------------------------- CSR build (bucket-first)
__global__ __launch_bounds__(256) void hist_b(const int* __restrict__ dstv, int E, int nbuckets, int* __restrict__ bcnt){
    __shared__ int h[NB_MAX];
    int b0 = blockIdx.x * ECHUNK;
    int b1 = min(b0 + ECHUNK, E);
    for (int i = threadIdx.x; i < nbuckets; i += 256) h[i] = 0;
    __syncthreads();
    for (int i = b0 + threadIdx.x; i < b1; i += 256)
        atomicAdd(&h[dstv[i] >> BSHIFT], 1);
    __syncthreads();
    for (int i = threadIdx.x; i < nbuckets; i += 256){
        int c = h[i];
        if (c) atomicAdd(&bcnt[i], c);
    }
}

__global__ __launch_bounds__(256) void scan_b(const int* __restrict__ bcnt, int nb, int E, int N,
                                              int* __restrict__ boffs, int* __restrict__ bcur, int* __restrict__ row_start){
    __shared__ int sh[256];
    int t = threadIdx.x;
    int v = (t < nb) ? bcnt[t] : 0;
    sh[t] = v; __syncthreads();
    for (int off = 1; off < 256; off <<= 1){
        int u = (t >= off) ? sh[t-off] : 0;
        __syncthreads();
        sh[t] += u;
        __syncthreads();
    }
    int ex = sh[t] - v;
    if (t < nb){ boffs[t] = ex; bcur[t] = ex; }
    if (t == 0){ boffs[nb] = E; row_start[N] = E; }
}

__global__ __launch_bounds__(256) void bin_edges_priv(const int* __restrict__ srcv, const int* __restrict__ dstv, int E,
                                                      int nbuckets, int* __restrict__ bcur, int2* __restrict__ pairs){
    __shared__ int cnt[NB_MAX];
    __shared__ int base[NB_MAX];
    int b0 = blockIdx.x * ECHUNK;
    int b1 = min(b0 + ECHUNK, E);
    for (int i = threadIdx.x; i < nbuckets; i += 256) cnt[i] = 0;
    __syncthreads();
    for (int i = b0 + threadIdx.x; i < b1; i += 256)
        atomicAdd(&cnt[dstv[i] >> BSHIFT], 1);
    __syncthreads();
    for (int i = threadIdx.x; i < nbuckets; i += 256){
        int c = cnt[i];
        base[i] = c ? atomicAdd(&bcur[i], c) : 0;
    }
    __syncthreads();
    for (int i = threadIdx.x; i < nbuckets; i += 256) cnt[i] = 0;
    __syncthreads();
    for (int i = b0 + threadIdx.x; i < b1; i += 256){
        int d = dstv[i];
        int bk = d >> BSHIFT;
        int loc = atomicAdd(&cnt[bk], 1);
        pairs[base[bk] + loc] = make_int2(d, srcv[i]);
    }
}

__global__ __launch_bounds__(256) void fill_bucket2(const int2* __restrict__ pairs, const int* __restrict__ boffs,
                                                    int* __restrict__ row_start, int* __restrict__ col_idx, int N){
    __shared__ int cur[BNODES];
    __shared__ int sh[256];
    int b  = blockIdx.x;
    int n0 = b << BSHIFT;
    int nn = min(BNODES, N - n0);
    int s = boffs[b], e = boffs[b+1];
    int t = threadIdx.x;
    cur[2*t]   = 0;
    cur[2*t+1] = 0;
    __syncthreads();
    for (int i = s + t; i < e; i += 256)
        atomicAdd(&cur[pairs[i].x - n0], 1);
    __syncthreads();
    int c0 = cur[2*t], c1 = cur[2*t+1];
    int s2 = c0 + c1;
    sh[t] = s2; __syncthreads();
    for (int off = 1; off < 256; off <<= 1){
        int u = (t >= off) ? sh[t-off] : 0;
        __syncthreads();
        sh[t] += u;
        __syncthreads();
    }
    int ex = sh[t] - s2;
    __syncthreads();
    cur[2*t]   = s + ex;
    cur[2*t+1] = s + ex + c0;
    __syncthreads();
    for (int i = t; i < nn; i += 256) row_start[n0 + i] = cur[i];
    __syncthreads();
    for (int i = s + t; i < e; i += 256){
        int2 p = pairs[i];
        int loc = atomicAdd(&cur[p.x - n0], 1);
        col_idx[loc] = p.y;
    }
}

__global__ __launch_bounds__(256) void flag_users(const int* __restrict__ uid, int B, int* __restrict__ flag){
    int i = blockIdx.x*256 + threadIdx.x;
    if (i < B) flag[uid[i]] = 1;
}

__global__ __launch_bounds__(256) void compact_flags(const int* __restrict__ flag, int N, int* __restrict__ list, int* __restrict__ cnt){
    int i = blockIdx.x*256 + threadIdx.x;
    if (i < N && flag[i]){ int p = atomicAdd(cnt, 1); list[p] = i; }
}

// ---------------------------------------------------------------- x -> fp16 copy (for layer-0 gather)
__global__ __launch_bounds__(256) void convert_fp16(const float* __restrict__ in, __half* __restrict__ out, long n8){
    long t = (long)blockIdx.x*256 + threadIdx.x;
    if (t >= n8) return;
    long i = t*8;
    float4 a = *(const float4*)(in + i);
    float4 b = *(const float4*)(in + i + 4);
    union { __half2 h[4]; float4 f; } u;
    u.h[0] = __floats2half2_rn(a.x, a.y);
    u.h[1] = __floats2half2_rn(a.z, a.w);
    u.h[2] = __floats2half2_rn(b.x, b.y);
    u.h[3] = __floats2half2_rn(b.z, b.w);
    *(float4*)(out + i) = u.f;
}

// ---------------------------------------------------------------- fused weight prep (one launch)
// all MFMA weights stored as bf16 hi/lo in [n][k] layout (k contiguous, stride 256)
// [0,32768)        wt0 : k<128 w_l0, else w_r0
// [32768,65536)    wt1 : k<128 w_l1, else w_r1
// [65536,163840)   wg  : w_ih rows (i,g,o), 384 x 256
// [163840,196608)  wc0h: wc0 direct [128][256]
// [196608,204800)  wtc1: fp32 transpose [128][64] (MODE-4 fp32 gemm)
// [204800,205184)  bias: bsum + ohtab
__global__ __launch_bounds__(256) void prep_all(const float* __restrict__ w_l0, const float* __restrict__ w_r0,
                                                const float* __restrict__ w_l1, const float* __restrict__ w_r1,
                                                const float* __restrict__ wc0,  const float* __restrict__ wc1,
                                                const float* __restrict__ w_ih, const float* __restrict__ b_ih,
                                                const float* __restrict__ b_hh,
                                                short* __restrict__ wt0h, short* __restrict__ wt0l,
                                                short* __restrict__ wt1h, short* __restrict__ wt1l,
                                                short* __restrict__ wgh,  short* __restrict__ wgl,
                                                short* __restrict__ wc0h, short* __restrict__ wc0l,
                                                float* __restrict__ wtc1,
                                                float* __restrict__ bsum, float* __restrict__ ohtab){
    int idx = blockIdx.x*256 + threadIdx.x;
    if (idx < 32768){
        int n = idx >> 8, k = idx & 255;
        float f = (k < 128) ? w_l0[n*128 + k] : w_r0[n*128 + (k - 128)];
        short h, l; split_bf16(f, h, l);
        wt0h[idx] = h; wt0l[idx] = l;
    } else if (idx < 65536){
        int i = idx - 32768;
        int n = i >> 8, k = i & 255;
        float f = (k < 128) ? w_l1[n*128 + k] : w_r1[n*128 + (k - 128)];
        short h, l; split_bf16(f, h, l);
        wt1h[i] = h; wt1l[i] = l;
    } else if (idx < 163840){
        int i = idx - 65536;
        int n = i >> 8, k = i & 255;       // n in [0,384)
        int j = n + ((n >= 128) ? 128 : 0);
        float f = w_ih[j*261 + k];
        short h, l; split_bf16(f, h, l);
        wgh[i] = h; wgl[i] = l;
    } else if (idx < 196608){
        int i = idx - 163840;
        float f = wc0[i];                  // [128][256] already [n][k]
        short h, l; split_bf16(f, h, l);
        wc0h[i] = h; wc0l[i] = l;
    } else if (idx < 204800){
        int i = idx - 196608;
        int j = i >> 7, k = i & 127;
        wtc1[k*64 + j] = wc1[j*128 + k];
    } else if (idx < 205184){
        int jj = idx - 204800;
        int j = jj + ((jj >= 128) ? 128 : 0);
        bsum[jj] = b_ih[j] + b_hh[j];
        for (int r = 0; r < 5; ++r) ohtab[r*384 + jj] = w_ih[j*261 + 256 + r];
    }
}

// ---------------------------------------------------------------- layer-0 mean aggregation (fp16 gather, fp32 accum)
__device__ __forceinline__ void accumh(float4& a0, float4& a1, float4 v){
    const __half2* h = (const __half2*)&v;
    float2 f0 = __half22float2(h[0]);
    float2 f1 = __half22float2(h[1]);
    float2 f2 = __half22float2(h[2]);
    float2 f3 = __half22float2(h[3]);
    a0.x += f0.x; a0.y += f0.y; a0.z += f1.x; a0.w += f1.y;
    a1.x += f2.x; a1.y += f2.y; a1.z += f3.x; a1.w += f3.y;
}

__global__ __launch_bounds__(256) void aggregate_h16(const __half* __restrict__ feat, const int* __restrict__ row_start,
                                                     const int* __restrict__ col_idx,
                                                     float* __restrict__ outmean, int N){
    int wave = (blockIdx.x*256 + threadIdx.x) >> 6;
    if (wave >= N) return;
    int lane = threadIdx.x & 63;
    int g  = lane >> 4;
    int sl = lane & 15;
    int s = row_start[wave], e = row_start[wave+1];
    const float4* f16 = (const float4*)feat;
    float4 a0 = make_float4(0.f,0.f,0.f,0.f);
    float4 a1 = make_float4(0.f,0.f,0.f,0.f);
    int i = s + g;
    for (; i + 12 < e; i += 16){
        int s0 = col_idx[i];
        int s1 = col_idx[i+4];
        int s2 = col_idx[i+8];
        int s3 = col_idx[i+12];
        float4 v0 = f16[(long)s0*16 + sl];
        float4 v1 = f16[(long)s1*16 + sl];
        float4 v2 = f16[(long)s2*16 + sl];
        float4 v3 = f16[(long)s3*16 + sl];
        accumh(a0, a1, v0);
        accumh(a0, a1, v1);
        accumh(a0, a1, v2);
        accumh(a0, a1, v3);
    }
    for (; i < e; i += 4){
        float4 v0 = f16[(long)col_idx[i]*16 + sl];
        accumh(a0, a1, v0);
    }
    a0.x += __shfl_xor(a0.x, 16, 64); a0.x += __shfl_xor(a0.x, 32, 64);
    a0.y += __shfl_xor(a0.y, 16, 64); a0.y += __shfl_xor(a0.y, 32, 64);
    a0.z += __shfl_xor(a0.z, 16, 64); a0.z += __shfl_xor(a0.z, 32, 64);
    a0.w += __shfl_xor(a0.w, 16, 64); a0.w += __shfl_xor(a0.w, 32, 64);
    a1.x += __shfl_xor(a1.x, 16, 64); a1.x += __shfl_xor(a1.x, 32, 64);
    a1.y += __shfl_xor(a1.y, 16, 64); a1.y += __shfl_xor(a1.y, 32, 64);
    a1.z += __shfl_xor(a1.z, 16, 64); a1.z += __shfl_xor(a1.z, 32, 64);
    a1.w += __shfl_xor(a1.w, 16, 64); a1.w += __shfl_xor(a1.w, 32, 64);
    if (g == 0){
        float inv = 1.f / fmaxf((float)(e - s), 1.f);
        a0.x *= inv; a0.y *= inv; a0.z *= inv; a0.w *= inv;
        a1.x *= inv; a1.y *= inv; a1.z *= inv; a1.w *= inv;
        float4* om = (float4*)(outmean + (long)wave*128 + sl*8);
        om[0] = a0;
        om[1] = a1;
    }
}

// ---------------------------------------------------------------- layer-1 mean aggregation (fp32 gather, compacted list)
__global__ __launch_bounds__(256) void aggregate_k(const float* __restrict__ feat, const int* __restrict__ row_start,
                                                   const int* __restrict__ col_idx,
                                                   const int* __restrict__ list, const int* __restrict__ cnt,
                                                   float* __restrict__ outmean, int N){
    int wave = (blockIdx.x*256 + threadIdx.x) >> 6;
    int lane = threadIdx.x & 63;
    if (wave >= *cnt) return;
    int node = list[wave];
    int s = row_start[node], e = row_start[node+1];
    int half = lane >> 5;
    int sl   = lane & 31;
    const float4* feat4 = (const float4*)feat;
    float4 a0 = make_float4(0.f,0.f,0.f,0.f);
    float4 a1 = make_float4(0.f,0.f,0.f,0.f);
    int i = s + half;
    for (; i + 6 < e; i += 8){
        int s0 = col_idx[i];
        int s1 = col_idx[i+2];
        int s2 = col_idx[i+4];
        int s3 = col_idx[i+6];
        float4 v0 = feat4[(long)s0*32 + sl];
        float4 v1 = feat4[(long)s1*32 + sl];
        float4 v2 = feat4[(long)s2*32 + sl];
        float4 v3 = feat4[(long)s3*32 + sl];
        a0.x += v0.x + v1.x; a0.y += v0.y + v1.y; a0.z += v0.z + v1.z; a0.w += v0.w + v1.w;
        a1.x += v2.x + v3.x; a1.y += v2.y + v3.y; a1.z += v2.z + v3.z; a1.w += v2.w + v3.w;
    }
    for (; i < e; i += 2){
        int s0 = col_idx[i];
        float4 v0 = feat4[(long)s0*32 + sl];
        a0.x += v0.x; a0.y += v0.y; a0.z += v0.z; a0.w += v0.w;
    }
    a0.x += a1.x; a0.y += a1.y; a0.z += a1.z; a0.w += a1.w;
    a0.x += __shfl_xor(a0.x, 32, 64);
    a0.y += __shfl_xor(a0.y, 32, 64);
    a0.z += __shfl_xor(a0.z, 32, 64);
    a0.w += __shfl_xor(a0.w, 32, 64);
    if (half == 0){
        float inv = 1.f / fmaxf((float)(e - s), 1.f);
        a0.x *= inv; a0.y *= inv; a0.z *= inv; a0.w *= inv;
        ((float4*)outmean)[(long)node*32 + sl] = a0;
    }
}

// ---------------------------------------------------------------- MODE-0 GEMM via split-bf16 MFMA
#define AROW 40
__global__ __launch_bounds__(256) void gemm0_mfma(const float* __restrict__ mean0, const float* __restrict__ x,
                                                  const short* __restrict__ wh, const short* __restrict__ wl,
                                                  const float* __restrict__ bias, float* __restrict__ out, int M){
    __shared__ __align__(16) short Ah[64*AROW];
    __shared__ __align__(16) short Al[64*AROW];
    __shared__ __align__(16) short Wh[128*AROW];
    __shared__ __align__(16) short Wl[128*AROW];

    const int tid  = threadIdx.x;
    const int row0 = blockIdx.x * 64;
    const int wave = tid >> 6, lane = tid & 63;
    const int lm = lane & 15, quad = lane >> 4;

    f32x4 acc[8];
    #pragma unroll
    for (int t = 0; t < 8; ++t) acc[t] = (f32x4){0.f, 0.f, 0.f, 0.f};

    for (int ko = 0; ko < 256; ko += KC){
        const float* Asrc = (ko < 128) ? (mean0 + ko) : (x + (ko - 128));
        #pragma unroll
        for (int it = 0; it < 2; ++it){
            int idx = it*256 + tid;
            int r = idx >> 3, k4 = idx & 7;
            int grow = row0 + r; if (grow >= M) grow = M - 1;
            float4 v = *(const float4*)(Asrc + (long)grow*128 + k4*4);
            union { short s[4]; int2 p; } ph, pl;
            split_bf16(v.x, ph.s[0], pl.s[0]);
            split_bf16(v.y, ph.s[1], pl.s[1]);
            split_bf16(v.z, ph.s[2], pl.s[2]);
            split_bf16(v.w, ph.s[3], pl.s[3]);
            *(int2*)&Ah[r*AROW + k4*4] = ph.p;
            *(int2*)&Al[r*AROW + k4*4] = pl.p;
        }
        #pragma unroll
        for (int it = 0; it < 2; ++it){
            int idx = it*256 + tid;
            int n = idx >> 2, q = idx & 3;
            int4 vh = *(const int4*)(wh + (long)n*256 + ko + q*8);
            *(int4*)&Wh[n*AROW + q*8] = vh;
            int4 vlo = *(const int4*)(wl + (long)n*256 + ko + q*8);
            *(int4*)&Wl[n*AROW + q*8] = vlo;
        }
        __syncthreads();

        bf16x8 ah = *(const bf16x8*)&Ah[(wave*16 + lm)*AROW + quad*8];
        bf16x8 al = *(const bf16x8*)&Al[(wave*16 + lm)*AROW + quad*8];
        #pragma unroll
        for (int t = 0; t < 8; ++t){
            bf16x8 bh = *(const bf16x8*)&Wh[(t*16 + lm)*AROW + quad*8];
            bf16x8 bl = *(const bf16x8*)&Wl[(t*16 + lm)*AROW + quad*8];
            acc[t] = __builtin_amdgcn_mfma_f32_16x16x32_bf16(ah, bh, acc[t], 0, 0, 0);
            acc[t] = __builtin_amdgcn_mfma_f32_16x16x32_bf16(ah, bl, acc[t], 0, 0, 0);
            acc[t] = __builtin_amdgcn_mfma_f32_16x16x32_bf16(al, bh, acc[t], 0, 0, 0);
        }
        __syncthreads();
    }

    #pragma unroll
    for (int t = 0; t < 8; ++t){
        int col = t*16 + lm;
        float b = bias[col];
        #pragma unroll
        for (int r = 0; r < 4; ++r){
            int row = row0 + wave*16 + quad*4 + r;
            if (row < M) out[(long)row*128 + col] = fmaxf(acc[t][r] + b, 0.f);
        }
    }
}

// ---------------------------------------------------------------- B-row GEMMs via split-bf16 MFMA
// MODE 1: ue    = clip([mean1|h][uid] @ wt1^T + b_l1)              N=128
// MODE 2: gates =      [ue|clip(x[uid])] @ wg^T + bsum + onehot    N=384 (gridDim.y=3)
// MODE 3: z0    = relu([ue|lstm] @ wc0^T + bc0)                    N=128
template<int MODE>
__global__ __launch_bounds__(256) void gemmB_mfma(const float* __restrict__ a0, const float* __restrict__ a1,
                                                  const int* __restrict__ g,
                                                  const short* __restrict__ wh, const short* __restrict__ wl,
                                                  const float* __restrict__ bias, const float* __restrict__ ohtab,
                                                  const int* __restrict__ roles,
                                                  float* __restrict__ out, int ncolsOut, int M){
    __shared__ __align__(16) short Ah[64*AROW];
    __shared__ __align__(16) short Al[64*AROW];
    __shared__ __align__(16) short Wh[128*AROW];
    __shared__ __align__(16) short Wl[128*AROW];

    const int tid  = threadIdx.x;
    const int row0 = blockIdx.x * 64;
    const int col0 = blockIdx.y * 128;
    const int wave = tid >> 6, lane = tid & 63;
    const int lm = lane & 15, quad = lane >> 4;

    f32x4 acc[8];
    #pragma unroll
    for (int t = 0; t < 8; ++t) acc[t] = (f32x4){0.f, 0.f, 0.f, 0.f};

    for (int ko = 0; ko < 256; ko += KC){
        #pragma unroll
        for (int it = 0; it < 2; ++it){
            int idx = it*256 + tid;
            int r = idx >> 3, k4 = idx & 7;
            int grow = row0 + r; if (grow >= M) grow = M - 1;
            int k = ko + k4*4;
            float4 v;
            if constexpr (MODE == 1){
                int node = g[grow];
                const float* p = (k < 128) ? a0 + (long)node*128 + k : a1 + (long)node*128 + (k-128);
                v = *(const float4*)p;
            } else if constexpr (MODE == 2){
                if (k < 128) v = *(const float4*)(a0 + (long)grow*128 + k);
                else {
                    int node = g[grow];
                    v = *(const float4*)(a1 + (long)node*128 + (k-128));
                    v.x = clipf(v.x); v.y = clipf(v.y); v.z = clipf(v.z); v.w = clipf(v.w);
                }
            } else {
                const float* p = (k < 128) ? a0 + (long)grow*128 + k : a1 + (long)grow*128 + (k-128);
                v = *(const float4*)p;
            }
            union { short s[4]; int2 p; } ph, pl;
            split_bf16(v.x, ph.s[0], pl.s[0]);
            split_bf16(v.y, ph.s[1], pl.s[1]);
            split_bf16(v.z, ph.s[2], pl.s[2]);
            split_bf16(v.w, ph.s[3], pl.s[3]);
            *(int2*)&Ah[r*AROW + k4*4] = ph.p;
            *(int2*)&Al[r*AROW + k4*4] = pl.p;
        }
        #pragma unroll
        for (int it = 0; it < 2; ++it){
            int idx = it*256 + tid;
            int n = idx >> 2, q = idx & 3;
            int4 vh = *(const int4*)(wh + (long)(col0 + n)*256 + ko + q*8);
            *(int4*)&Wh[n*AROW + q*8] = vh;
            int4 vlo = *(const int4*)(wl + (long)(col0 + n)*256 + ko + q*8);
            *(int4*)&Wl[n*AROW + q*8] = vlo;
        }
        __syncthreads();

        bf16x8 ah = *(const bf16x8*)&Ah[(wave*16 + lm)*AROW + quad*8];
        bf16x8 al = *(const bf16x8*)&Al[(wave*16 + lm)*AROW + quad*8];
        #pragma unroll
        for (int t = 0; t < 8; ++t){
            bf16x8 bh = *(const bf16x8*)&Wh[(t*16 + lm)*AROW + quad*8];
            bf16x8 bl = *(const bf16x8*)&Wl[(t*16 + lm)*AROW + quad*8];
            acc[t] = __builtin_amdgcn_mfma_f32_16x16x32_bf16(ah, bh, acc[t], 0, 0, 0);
            acc[t] = __builtin_amdgcn_mfma_f32_16x16x32_bf16(ah, bl, acc[t], 0, 0, 0);
            acc[t] = __builtin_amdgcn_mfma_f32_16x16x32_bf16(al, bh, acc[t], 0, 0, 0);
        }
        __syncthreads();
    }

    #pragma unroll
    for (int t = 0; t < 8; ++t){
        int gcol = col0 + t*16 + lm;
        float b = bias[gcol];
        #pragma unroll
        for (int r = 0; r < 4; ++r){
            int row = row0 + wave*16 + quad*4 + r;
            if (row >= M) continue;
            float v = acc[t][r] + b;
            if constexpr (MODE == 1)      v = clipf(v);
            else if constexpr (MODE == 2) v = v + ohtab[roles[row]*384 + gcol];
            else                          v = fmaxf(v, 0.f);
            out[(long)row*ncolsOut + gcol] = v;
        }
    }
}

// ---------------------------------------------------------------- generic fp32 GEMM (MODE 4 only)
struct GemmArgs {
    const float* a0; const float* wt;
    const float* bias;
    float* out; int M;
};

__global__ __launch_bounds__(THREADS) void gemm4_k(GemmArgs A){
    constexpr int BM = 64;
    constexpr int BN = 64;
    constexpr int TN = 4;
    constexpr int CT = BN / TN;          // 16
    constexpr int RT = THREADS / CT;     // 16
    constexpr int TM = BM / RT;          // 4
    constexpr int KTOT = 128;
    constexpr int AST = BM + 4;

    __shared__ __align__(16) float As[KC][AST];
    __shared__ __align__(16) float Ws[KC][BN];

    const int tid  = threadIdx.x;
    const int row0 = blockIdx.x * BM;
    const int c  = tid % CT;
    const int rt = tid / CT;

    float acc[TM][TN];
    #pragma unroll
    for (int i = 0; i < TM; ++i)
        #pragma unroll
        for (int j = 0; j < TN; ++j) acc[i][j] = 0.f;

    for (int ko = 0; ko < KTOT; ko += KC){
        #pragma unroll
        for (int it = 0; it < 2; ++it){
            int idx = it*THREADS + tid;
            int r  = idx >> 3;
            int k4 = idx & 7;
            int grow = row0 + r; if (grow >= A.M) grow = A.M - 1;
            float4 v = *(const float4*)(A.a0 + (long)grow*128 + ko + k4*4);
            As[k4*4+0][r] = v.x;
            As[k4*4+1][r] = v.y;
            As[k4*4+2][r] = v.z;
            As[k4*4+3][r] = v.w;
        }
        #pragma unroll
        for (int it = 0; it < 2; ++it){
            int idx = it*THREADS + tid;
            int kk = idx / (BN/4);
            int c4 = idx % (BN/4);
            float4 v = *(const float4*)&A.wt[(long)(ko+kk)*BN + c4*4];
            *(float4*)&Ws[kk][c4*4] = v;
        }
        __syncthreads();
        #pragma unroll
        for (int kk = 0; kk < KC; ++kk){
            float4 wv = *(const float4*)&Ws[kk][c*4];
            float w[TN] = {wv.x, wv.y, wv.z, wv.w};
            float a[TM];
            float4 av = *(const float4*)&As[kk][rt*TM];
            a[0] = av.x; a[1] = av.y; a[2] = av.z; a[3] = av.w;
            #pragma unroll
            for (int i = 0; i < TM; ++i)
                #pragma unroll
                for (int j = 0; j < TN; ++j) acc[i][j] = fmaf(a[i], w[j], acc[i][j]);
        }
        __syncthreads();
    }

    #pragma unroll
    for (int i = 0; i < TM; ++i){
        int grow = row0 + rt*TM + i;
        if (grow >= A.M) continue;
        #pragma unroll
        for (int j = 0; j < TN; ++j){
            int gcol = c*4 + j;
            A.out[(long)grow*64 + gcol] = fmaxf(acc[i][j] + A.bias[gcol], 0.f);
        }
    }
}

// ---------------------------------------------------------------- LSTM activation (f-gate dead, c0=0)
__global__ __launch_bounds__(256) void lstm_act(const float* __restrict__ gates, float* __restrict__ lstm, int B){
    int idx = blockIdx.x*256 + threadIdx.x;
    if (idx >= B*128) return;
    int b = idx >> 7, j = idx & 127;
    const float* gr = gates + (long)b*384;
    float i_ = gr[j], g_ = gr[128 + j], o_ = gr[256 + j];
    float si = 1.f/(1.f + expf(-i_));
    float c  = si * tanhf(g_);
    float so = 1.f/(1.f + expf(-o_));
    lstm[idx] = clipf(so * tanhf(c));
}

// ---------------------------------------------------------------- final tiny GEMM [B,64]@[64,5]
__global__ __launch_bounds__(256) void out_k(const float* __restrict__ z1, const float* __restrict__ wc2, const float* __restrict__ bc2,
                                             float* __restrict__ out, int B){
    int idx = blockIdx.x*256 + threadIdx.x;
    int b = idx >> 3, r = idx & 7;
    if (b >= B || r >= 5) return;
    const float* zr = z1 + (long)b*64;
    const float* wr = wc2 + r*64;
    float acc = bc2[r];
    #pragma unroll 16
    for (int k = 0; k < 64; ++k) acc = fmaf(zr[k], wr[k], acc);
    out[b*5 + r] = acc;
}

// ----------------------------------------------------------------
extern "C" void kernel_launch(void* const* d_in, const int* in_sizes, int n_in,
                              void* d_out, int out_size, void* d_ws, size_t ws_size,
                              hipStream_t stream){
    const float* x     = (const float*)d_in[0];
    const int*   edge  = (const int*)  d_in[1];
    const int*   uid   = (const int*)  d_in[2];
    const int*   roles = (const int*)  d_in[3];
    const float* w_l0  = (const float*)d_in[4];
    const float* b_l0  = (const float*)d_in[5];
    const float* w_r0  = (const float*)d_in[6];
    const float* w_l1  = (const float*)d_in[7];
    const float* b_l1  = (const float*)d_in[8];
    const float* w_r1  = (const float*)d_in[9];
    const float* w_ih  = (const float*)d_in[10];
    // d_in[11] = w_hh: dead (h0 = 0)
    const float* b_ih  = (const float*)d_in[12];
    const float* b_hh  = (const float*)d_in[13];
    const float* wc0   = (const float*)d_in[14];
    const float* bc0   = (const float*)d_in[15];
    const float* wc1   = (const float*)d_in[16];
    const float* bc1   = (const float*)d_in[17];
    const float* wc2   = (const float*)d_in[18];
    const float* bc2   = (const float*)d_in[19];

    const int N = in_sizes[0] / 128;
    const int E = in_sizes[1] / 2;
    const int B = in_sizes[2];
    const int nbuckets = (N + BNODES - 1) >> BSHIFT;

    char* ws = (char*)d_ws;
    size_t off = 0;
    auto alloc = [&](size_t bytes) -> void* {
        void* p = ws + off; off += (bytes + 255) & ~(size_t)255; return p;
    };
    float* arenaA   = (float*)alloc((size_t)N*128*4);   // mean0 -> mean1 -> gates
    float* arenaB   = (float*)alloc((size_t)N*128*4);   // pairs -> h -> lstm/z0/z1
    float* ue       = (float*)alloc((size_t)B*128*4);
    __half* xh      = (__half*)alloc((size_t)N*128*2);
    // zero-init region (one memset): flag, ucnt, bcnt
    int*   flag     = (int*)  alloc((size_t)N*4);
    int*   ucnt     = (int*)  alloc(256);
    int*   bcnt     = (int*)  alloc(NB_MAX*4);
    char*  zero_end = ws + off;
    int*   row_start= (int*)  alloc((size_t)(N+1)*4);
    int*   boffs    = (int*)  alloc((size_t)(NB_MAX+1)*4);
    int*   bcur     = (int*)  alloc((size_t)NB_MAX*4);
    int*   col_idx  = (int*)  alloc((size_t)E*4);
    int*   ulist    = (int*)  alloc((size_t)B*4);
    short* wt0h     = (short*)alloc(128*256*2);
    short* wt0l     = (short*)alloc(128*256*2);
    short* wt1h     = (short*)alloc(128*256*2);
    short* wt1l     = (short*)alloc(128*256*2);
    short* wgh      = (short*)alloc(384*256*2);
    short* wgl      = (short*)alloc(384*256*2);
    short* wc0h     = (short*)alloc(128*256*2);
    short* wc0l     = (short*)alloc(128*256*2);
    float* wtc1     = (float*)alloc(128*64*4);
    float* bsum     = (float*)alloc(384*4);
    float* ohtab    = (float*)alloc(5*384*4);

    int2*  pairs = (int2*)arenaB;                // consumed by fill_bucket2 before h is written
    float* mean0 = arenaA;
    float* h     = arenaB;
    float* mean1 = arenaA;
    float* gates = arenaA;
    float* lstm  = arenaB;
    float* z0    = arenaB + (size_t)B*128;
    float* z1    = arenaB + (size_t)B*128*2;

    hipMemsetAsync(flag, 0, (size_t)(zero_end - (char*)flag), stream);

    const int gEC = (E + ECHUNK - 1)/ECHUNK;

    hist_b<<<gEC, 256, 0, stream>>>(edge + E, E, nbuckets, bcnt);
    scan_b<<<1, 256, 0, stream>>>(bcnt, nbuckets, E, N, boffs, bcur, row_start);
    bin_edges_priv<<<gEC, 256, 0, stream>>>(edge, edge + E, E, nbuckets, bcur, pairs);
    fill_bucket2<<<nbuckets, 256, 0, stream>>>(pairs, boffs, row_start, col_idx, N);
    flag_users<<<(B + 255)/256, 256, 0, stream>>>(uid, B, flag);
    compact_flags<<<(N + 255)/256, 256, 0, stream>>>(flag, N, ulist, ucnt);

    convert_fp16<<<(N*128/8 + 255)/256, 256, 0, stream>>>(x, xh, (long)N*128/8);
    prep_all<<<802, 256, 0, stream>>>(w_l0, w_r0, w_l1, w_r1, wc0, wc1, w_ih, b_ih, b_hh,
                                      wt0h, wt0l, wt1h, wt1l, wgh, wgl, wc0h, wc0l,
                                      wtc1, bsum, ohtab);

    // layer 0: mean over all nodes (fp16 gather), then h = relu([mean0|x] @ wt0^T + b_l0) via MFMA
    aggregate_h16<<<(N + 3)/4, 256, 0, stream>>>(xh, row_start, col_idx, mean0, N);
    gemm0_mfma<<<(N + 63)/64, 256, 0, stream>>>(mean0, x, wt0h, wt0l, b_l0, h, N);

    // layer 1: aggregation + dense only for user nodes (compacted list, fp32 gather)
    aggregate_k<<<(B + 3)/4, 256, 0, stream>>>(h, row_start, col_idx, ulist, ucnt, mean1, N);
    gemmB_mfma<1><<<dim3(B/64, 1), 256, 0, stream>>>(mean1, h, uid, wt1h, wt1l, b_l1, nullptr, nullptr, ue, 128, B);

    // LSTM gates (i,g,o only) + activation
    gemmB_mfma<2><<<dim3(B/64, 3), 256, 0, stream>>>(ue, x, uid, wgh, wgl, bsum, ohtab, roles, gates, 384, B);
    lstm_act<<<(B*128 + 255)/256, 256, 0, stream>>>(gates, lstm, B);

    // classifier MLP
    gemmB_mfma<3><<<dim3(B/64, 1), 256, 0, stream>>>(ue, lstm, nullptr, wc0h, wc0l, bc0, nullptr, nullptr, z0, 128, B);
    GemmArgs gz1 { z0, wtc1, bc1, z1, B };
    gemm4_k<<<B/64, THREADS, 0, stream>>>(gz1);
    out_k<<<(B*8 + 255)/256, 256, 0, stream>>>(z1, wc2, bc2, (float*)d_out, B);

    (void)n_in; (void)out_size; (void)ws_size;
}